// Round 6
// baseline (826.648 us; speedup 1.0000x reference)
//
#include <hip/hip_runtime.h>

// Shapes (fixed per reference)
#define BB    16
#define NNN   512
#define DDIM  256
#define HH    8
#define DKK   32
#define FFF   512
#define MROWS 8192   // B*N
#define LUTN  4096

using u16    = unsigned short;
using bf16x8 = __attribute__((ext_vector_type(8))) short;
using f32x4  = __attribute__((ext_vector_type(4))) float;

__device__ __forceinline__ float bf2f(u16 u) { return __uint_as_float(((unsigned)u) << 16); }
__device__ __forceinline__ u16 f2bf(float f) {
    unsigned u = __float_as_uint(f);
    return (u16)((u + 0x7fffu + ((u >> 16) & 1u)) >> 16);  // RNE
}

// ---------------------------------------------------------------------------
// h = x @ init_W + init_b   (x: (8192,2), W: (2,256))
__global__ __launch_bounds__(256) void init_embed_kernel(
    const float* __restrict__ x, const float* __restrict__ W,
    const float* __restrict__ b, float* __restrict__ h)
{
    size_t row = blockIdx.x;
    int c = threadIdx.x;
    float x0 = x[row * 2 + 0], x1 = x[row * 2 + 1];
    h[row * DDIM + c] = x0 * W[c] + x1 * W[DDIM + c] + b[c];
}

// ---------------------------------------------------------------------------
// Edge MLP is a scalar->R^8 piecewise-linear function: build a LUT once.
__global__ __launch_bounds__(256) void build_lut_kernel(
    const float* __restrict__ eW1, const float* __restrict__ eb1,
    const float* __restrict__ eW2, const float* __restrict__ eb2,
    const float* __restrict__ eW3, const float* __restrict__ eb3,
    float* __restrict__ lut)  // (LUTN+1) x 8
{
    int i = blockIdx.x * 256 + threadIdx.x;
    if (i > LUTN) return;
    float e = (float)i * (1.0f / LUTN);
    float t1[16], t2[16];
    #pragma unroll
    for (int a = 0; a < 16; ++a) t1[a] = fmaxf(e * eW1[a] + eb1[a], 0.0f);
    #pragma unroll
    for (int j = 0; j < 16; ++j) {
        float s = eb2[j];
        #pragma unroll
        for (int a = 0; a < 16; ++a) s += t1[a] * eW2[a * 16 + j];
        t2[j] = fmaxf(s, 0.0f);
    }
    #pragma unroll
    for (int hd = 0; hd < 8; ++hd) {
        float s = eb3[hd];
        #pragma unroll
        for (int j = 0; j < 16; ++j) s += t2[j] * eW3[j * 8 + hd];
        lut[(size_t)i * 8 + hd] = s;
    }
}

// bias[hd][b][i][j] (bf16) = lerp(LUT, edge[b,i,j])
__global__ __launch_bounds__(256) void edge_bias_kernel(
    const float* __restrict__ edge, const float* __restrict__ lut,
    u16* __restrict__ bout)
{
    size_t idx = (size_t)blockIdx.x * 256 + threadIdx.x;  // over B*N*N = 4,194,304
    float e = edge[idx];
    float f = e * (float)LUTN;
    f = fminf(fmaxf(f, 0.0f), (float)LUTN - 0.0001f);
    int i0 = (int)f;
    float fr = f - (float)i0;
    const float4* r = (const float4*)(lut + (size_t)i0 * 8);
    float4 a0 = r[0], a1 = r[1], b0 = r[2], b1 = r[3];  // row i0, row i0+1
    float o[8];
    o[0] = a0.x + fr * (b0.x - a0.x);
    o[1] = a0.y + fr * (b0.y - a0.y);
    o[2] = a0.z + fr * (b0.z - a0.z);
    o[3] = a0.w + fr * (b0.w - a0.w);
    o[4] = a1.x + fr * (b1.x - a1.x);
    o[5] = a1.y + fr * (b1.y - a1.y);
    o[6] = a1.z + fr * (b1.z - a1.z);
    o[7] = a1.w + fr * (b1.w - a1.w);
    #pragma unroll
    for (int hd = 0; hd < 8; ++hd)
        bout[(size_t)hd * (size_t)BB * NNN * NNN + idx] = f2bf(o[hd]);
}

// ---------------------------------------------------------------------------
// Split-bf16 MFMA GEMM (f32-accurate): A = Ah + Al, B = Bh + Bl (bf16 pairs);
// C = Ah*Bh + Ah*Bl + Al*Bh  (error ~2^-18, f32-equivalent).
// C(8192 x Nc) = A(8192 x K) @ B(K x Nc) [+bias][relu][+res]
// Tile 128x64, BK=32, 4 waves (2x2), wave = 64x32 via 4x2 frags of 16x16x32.
#define GBM 128
#define GBN 64
#define GBK 32
#define LPAD 40   // u16 elems per LDS row (32 + 8 pad, keeps 16B alignment)

template <int BMODE>  // 0: plain row-major B (ldb); 1: QKV-packed weights
__global__ __launch_bounds__(256) void gemm_kernel(
    const float* __restrict__ A, int lda,
    const float* __restrict__ Bp, int ldb,
    const float* __restrict__ Wq, const float* __restrict__ Wk,
    const float* __restrict__ Wv, int layer,
    float* __restrict__ C, int ldc,
    const float* __restrict__ bias, int relu,
    const float* __restrict__ res, int ldr,
    int K)
{
    __shared__ u16 Ash[GBM][LPAD];
    __shared__ u16 Asl[GBM][LPAD];
    __shared__ u16 Bsh[GBN][LPAD];
    __shared__ u16 Bsl[GBN][LPAD];
    int m0 = blockIdx.y * GBM;
    int n0 = blockIdx.x * GBN;
    int tid = threadIdx.x;
    int lid = tid & 63, wid = tid >> 6;
    int wm = wid >> 1, wn = wid & 1;
    int l15 = lid & 15, l4 = lid >> 4;

    f32x4 acc[4][2] = {};

    for (int k0 = 0; k0 < K; k0 += GBK) {
        // stage A: 128x32 f32 -> hi/lo bf16
        #pragma unroll
        for (int j = 0; j < 4; ++j) {
            int idx = tid + 256 * j;           // 1024 float4s
            int row = idx >> 3, k4 = idx & 7;
            float4 v = *(const float4*)(A + (size_t)(m0 + row) * lda + k0 + k4 * 4);
            ushort4 wh, wl;
            wh.x = f2bf(v.x); wl.x = f2bf(v.x - bf2f(wh.x));
            wh.y = f2bf(v.y); wl.y = f2bf(v.y - bf2f(wh.y));
            wh.z = f2bf(v.z); wl.z = f2bf(v.z - bf2f(wh.z));
            wh.w = f2bf(v.w); wl.w = f2bf(v.w - bf2f(wh.w));
            *(ushort4*)&Ash[row][k4 * 4] = wh;
            *(ushort4*)&Asl[row][k4 * 4] = wl;
        }
        // stage B transposed: Bs[n][k]
        #pragma unroll
        for (int j = 0; j < 8; ++j) {
            int idx = tid + 256 * j;           // 2048 elems (32k x 64n)
            int kk = idx >> 6, nn = idx & 63;
            int gk = k0 + kk, gn = n0 + nn;
            float v;
            if (BMODE == 0) {
                v = Bp[(size_t)gk * ldb + gn];
            } else {
                int mat = gn >> 8, c8 = gn & 255, hd = c8 >> 5, dk = c8 & 31;
                const float* Wsel = (mat == 0) ? Wq : ((mat == 1) ? Wk : Wv);
                v = Wsel[(((size_t)layer * HH + hd) * DDIM + gk) * DKK + dk];
            }
            u16 hh = f2bf(v);
            Bsh[nn][kk] = hh;
            Bsl[nn][kk] = f2bf(v - bf2f(hh));
        }
        __syncthreads();
        bf16x8 afh[4], afl[4], bfh[2], bfl[2];
        #pragma unroll
        for (int mi = 0; mi < 4; ++mi) {
            afh[mi] = *(const bf16x8*)&Ash[wm * 64 + mi * 16 + l15][l4 * 8];
            afl[mi] = *(const bf16x8*)&Asl[wm * 64 + mi * 16 + l15][l4 * 8];
        }
        #pragma unroll
        for (int ni = 0; ni < 2; ++ni) {
            bfh[ni] = *(const bf16x8*)&Bsh[wn * 32 + ni * 16 + l15][l4 * 8];
            bfl[ni] = *(const bf16x8*)&Bsl[wn * 32 + ni * 16 + l15][l4 * 8];
        }
        #pragma unroll
        for (int mi = 0; mi < 4; ++mi)
            #pragma unroll
            for (int ni = 0; ni < 2; ++ni) {
                acc[mi][ni] = __builtin_amdgcn_mfma_f32_16x16x32_bf16(
                    afh[mi], bfh[ni], acc[mi][ni], 0, 0, 0);
                acc[mi][ni] = __builtin_amdgcn_mfma_f32_16x16x32_bf16(
                    afh[mi], bfl[ni], acc[mi][ni], 0, 0, 0);
                acc[mi][ni] = __builtin_amdgcn_mfma_f32_16x16x32_bf16(
                    afl[mi], bfh[ni], acc[mi][ni], 0, 0, 0);
            }
        __syncthreads();
    }
    // epilogue
    #pragma unroll
    for (int mi = 0; mi < 4; ++mi) {
        #pragma unroll
        for (int ni = 0; ni < 2; ++ni) {
            #pragma unroll
            for (int r = 0; r < 4; ++r) {
                int row = m0 + wm * 64 + mi * 16 + l4 * 4 + r;
                int col = n0 + wn * 32 + ni * 16 + l15;
                float v = acc[mi][ni][r];
                if (bias) v += bias[col];
                if (relu) v = fmaxf(v, 0.0f);
                if (res)  v += res[(size_t)row * ldr + col];
                C[(size_t)row * ldc + col] = v;
            }
        }
    }
}

// ---------------------------------------------------------------------------
// MFMA fused attention, split-bf16 scores. Block = (qtile 64, head, batch);
// 4 waves, each owns 16 q-rows. Scores S = Qh·Kh + Ql·Kh + Qh·Kl (~f32 exact)
// via TWO staging passes over the same 32 KB Ks buffer (hi pass, then lo pass)
// to stay under the 160 KB LDS limit. P bf16 via per-wave LDS; V bf16
// transposed; softmax in C-frags (reduce over l15 via shfl_xor 1,2,4,8).
__global__ __launch_bounds__(256) void attn_mfma_kernel(
    const float* __restrict__ qkv, const u16* __restrict__ bias,
    float* __restrict__ att)
{
    __shared__ u16 Ks[512][32];       // K[n][k] hi, then lo   32 KB
    __shared__ u16 Vt[32][520];       // V^T[dk][n] (+pad)     33 KB
    __shared__ u16 Pw[4][16][520];    // per-wave P[q][n]      66 KB
    int qt = blockIdx.x, hd = blockIdx.y, b = blockIdx.z;
    int tid = threadIdx.x, lid = tid & 63, w = tid >> 6;
    int l15 = lid & 15, l4 = lid >> 4;   // l4 in 0..3

    const float* base = qkv + (size_t)b * 512 * 768;
    // stage pass 1: K hi + V
    for (int idx = tid; idx < 512 * 32; idx += 256) {
        int n = idx >> 5, k = idx & 31;
        Ks[n][k] = f2bf(base[(size_t)n * 768 + 256 + hd * 32 + k]);
        Vt[k][n] = f2bf(base[(size_t)n * 768 + 512 + hd * 32 + k]);
    }
    __syncthreads();

    int qw0 = qt * 64 + w * 16;
    // Q A-frags hi/lo: row = l15, k = l4*8 + j
    bf16x8 afh, afl;
    {
        const float* qrow = base + (size_t)(qw0 + l15) * 768 + hd * 32 + l4 * 8;
        u16 th[8], tl[8];
        #pragma unroll
        for (int j = 0; j < 8; ++j) {
            float v = qrow[j];
            th[j] = f2bf(v);
            tl[j] = f2bf(v - bf2f(th[j]));
        }
        afh = *(bf16x8*)th;
        afl = *(bf16x8*)tl;
    }

    // scores pass 1: S = (Qh + Ql) · Kh  over 32 col-tiles
    f32x4 acc[32];
    #pragma unroll
    for (int ct = 0; ct < 32; ++ct) {
        bf16x8 bfr = *(const bf16x8*)&Ks[ct * 16 + l15][l4 * 8];
        f32x4 z = {0.0f, 0.0f, 0.0f, 0.0f};
        z = __builtin_amdgcn_mfma_f32_16x16x32_bf16(afh, bfr, z, 0, 0, 0);
        acc[ct] = __builtin_amdgcn_mfma_f32_16x16x32_bf16(afl, bfr, z, 0, 0, 0);
    }
    __syncthreads();   // all waves done reading Kh

    // stage pass 2: K lo residual into the same buffer
    for (int idx = tid; idx < 512 * 32; idx += 256) {
        int n = idx >> 5, k = idx & 31;
        float v = base[(size_t)n * 768 + 256 + hd * 32 + k];
        u16 hh = f2bf(v);
        Ks[n][k] = f2bf(v - bf2f(hh));
    }
    __syncthreads();

    // scores pass 2: S += Qh · Kl
    #pragma unroll
    for (int ct = 0; ct < 32; ++ct) {
        bf16x8 bfr = *(const bf16x8*)&Ks[ct * 16 + l15][l4 * 8];
        acc[ct] = __builtin_amdgcn_mfma_f32_16x16x32_bf16(afh, bfr, acc[ct], 0, 0, 0);
    }

    const float scale = 0.17677669529663687f;  // 1/sqrt(32)
    if (bias) {
        size_t brow = (((size_t)hd * BB + b) * NNN + qw0 + l4 * 4) * NNN + l15;
        #pragma unroll
        for (int ct = 0; ct < 32; ++ct)
            #pragma unroll
            for (int r = 0; r < 4; ++r)
                acc[ct][r] = acc[ct][r] * scale +
                             bf2f(bias[brow + (size_t)r * NNN + ct * 16]);
    } else {
        #pragma unroll
        for (int ct = 0; ct < 32; ++ct)
            #pragma unroll
            for (int r = 0; r < 4; ++r)
                acc[ct][r] *= scale;
    }

    // in-fragment softmax per row (rows = qw0 + l4*4 + r)
    float linv[4];
    #pragma unroll
    for (int r = 0; r < 4; ++r) {
        float m = acc[0][r];
        #pragma unroll
        for (int ct = 1; ct < 32; ++ct) m = fmaxf(m, acc[ct][r]);
        #pragma unroll
        for (int msk = 1; msk < 16; msk <<= 1) m = fmaxf(m, __shfl_xor(m, msk));
        float lsum = 0.0f;
        #pragma unroll
        for (int ct = 0; ct < 32; ++ct) {
            float p = __expf(acc[ct][r] - m);
            acc[ct][r] = p;
            lsum += p;
        }
        #pragma unroll
        for (int msk = 1; msk < 16; msk <<= 1) lsum += __shfl_xor(lsum, msk);
        linv[r] = 1.0f / lsum;
    }

    // P -> per-wave LDS (bf16, unnormalized)
    #pragma unroll
    for (int ct = 0; ct < 32; ++ct)
        #pragma unroll
        for (int r = 0; r < 4; ++r)
            Pw[w][l4 * 4 + r][ct * 16 + l15] = f2bf(acc[ct][r]);
    __syncthreads();  // ordering safety (per-wave region; barrier is cheap, once per block)

    // PV: O(16 x 32) = P(16 x 512) @ V(512 x 32)
    f32x4 oacc[2] = {};
    #pragma unroll
    for (int ks = 0; ks < 16; ++ks) {
        bf16x8 pa = *(const bf16x8*)&Pw[w][l15][ks * 32 + l4 * 8];
        #pragma unroll
        for (int ct2 = 0; ct2 < 2; ++ct2) {
            bf16x8 vb = *(const bf16x8*)&Vt[ct2 * 16 + l15][ks * 32 + l4 * 8];
            oacc[ct2] = __builtin_amdgcn_mfma_f32_16x16x32_bf16(pa, vb, oacc[ct2], 0, 0, 0);
        }
    }
    // epilogue: col = hd*32 + ct2*16 + l15, row = qw0 + l4*4 + r, scale by linv[r]
    #pragma unroll
    for (int ct2 = 0; ct2 < 2; ++ct2)
        #pragma unroll
        for (int r = 0; r < 4; ++r)
            att[((size_t)b * NNN + qw0 + l4 * 4 + r) * DDIM + hd * 32 + ct2 * 16 + l15] =
                oacc[ct2][r] * linv[r];
}

// ---------------------------------------------------------------------------
__global__ void zero_stats_kernel(float* stats)
{
    stats[threadIdx.x] = 0.0f;
    stats[256 + threadIdx.x] = 0.0f;
}

__global__ __launch_bounds__(256) void bn_stats_kernel(
    const float* __restrict__ X, float* __restrict__ stats)
{
    int c = threadIdx.x;
    size_t r0 = (size_t)blockIdx.x * 128;
    float s = 0.0f, ss = 0.0f;
    for (int r = 0; r < 128; ++r) {
        float v = X[(r0 + r) * DDIM + c];
        s += v; ss += v * v;
    }
    atomicAdd(&stats[c], s);
    atomicAdd(&stats[256 + c], ss);
}

__global__ __launch_bounds__(256) void bn_apply_kernel(
    const float* __restrict__ X, float* __restrict__ Y,
    const float* __restrict__ stats,
    const float* __restrict__ g, const float* __restrict__ bb)
{
    int c = threadIdx.x;
    float mean = stats[c] * (1.0f / MROWS);
    float var  = stats[256 + c] * (1.0f / MROWS) - mean * mean;
    float inv  = rsqrtf(var + 1e-5f);
    float gg = g[c] * inv;
    float off = bb[c] - mean * gg;
    size_t r0 = (size_t)blockIdx.x * 8;
    #pragma unroll
    for (int r = 0; r < 8; ++r) {
        size_t o = (r0 + r) * DDIM + c;
        Y[o] = X[o] * gg + off;
    }
}

__global__ __launch_bounds__(256) void graph_embed_kernel(
    const float* __restrict__ outh, float* __restrict__ outg)
{
    int c = threadIdx.x, b = blockIdx.x;
    float s = 0.0f;
    for (int n = 0; n < NNN; ++n)
        s += outh[((size_t)b * NNN + n) * DDIM + c];
    outg[b * DDIM + c] = s * (1.0f / NNN);
}

// ---------------------------------------------------------------------------
extern "C" void kernel_launch(void* const* d_in, const int* in_sizes, int n_in,
                              void* d_out, int out_size, void* d_ws, size_t ws_size,
                              hipStream_t stream)
{
    const float* x     = (const float*)d_in[0];
    const float* edge  = (const float*)d_in[1];
    const float* initW = (const float*)d_in[2];
    const float* initb = (const float*)d_in[3];
    const float* Wq    = (const float*)d_in[4];
    const float* Wk    = (const float*)d_in[5];
    const float* Wv    = (const float*)d_in[6];
    const float* Wo    = (const float*)d_in[7];
    const float* eW1   = (const float*)d_in[8];
    const float* eb1   = (const float*)d_in[9];
    const float* eW2   = (const float*)d_in[10];
    const float* eb2   = (const float*)d_in[11];
    const float* eW3   = (const float*)d_in[12];
    const float* eb3   = (const float*)d_in[13];
    const float* bn1g  = (const float*)d_in[14];
    const float* bn1b  = (const float*)d_in[15];
    const float* ffW1  = (const float*)d_in[16];
    const float* ffb1  = (const float*)d_in[17];
    const float* ffW2  = (const float*)d_in[18];
    const float* ffb2  = (const float*)d_in[19];
    const float* bn2g  = (const float*)d_in[20];
    const float* bn2b  = (const float*)d_in[21];

    char* ws = (char*)d_ws;
    float* h     = (float*)(ws);                           //  8 MB
    float* h2    = (float*)(ws + ((size_t)8 << 20));       //  8 MB
    float* qkv   = (float*)(ws + ((size_t)16 << 20));      // 24 MB
    float* attb  = (float*)(ws + ((size_t)40 << 20));      //  8 MB
    float* ff    = (float*)(ws + ((size_t)48 << 20));      // 16 MB
    float* stats = (float*)(ws + ((size_t)64 << 20));      //  2 KB
    float* lut   = (float*)(ws + ((size_t)64 << 20) + 4096); // ~128 KB
    u16*   bias  = (u16*)  (ws + ((size_t)65 << 20));      // 64 MB
    float* outh  = (float*)d_out;
    float* outg  = outh + (size_t)MROWS * DDIM;

    init_embed_kernel<<<MROWS, 256, 0, stream>>>(x, initW, initb, h);
    build_lut_kernel<<<17, 256, 0, stream>>>(eW1, eb1, eW2, eb2, eW3, eb3, lut);
    edge_bias_kernel<<<(BB * NNN * NNN) / 256, 256, 0, stream>>>(edge, lut, bias);

    for (int l = 0; l < 3; ++l) {
        // QKV projection: (8192x256) @ packed (256x768)
        gemm_kernel<1><<<dim3(768 / GBN, MROWS / GBM), 256, 0, stream>>>(
            h, 256, nullptr, 0, Wq, Wk, Wv, l, qkv, 768,
            nullptr, 0, nullptr, 0, 256);
        // fused MFMA attention (split-bf16 scores)
        attn_mfma_kernel<<<dim3(8, 8, 16), 256, 0, stream>>>(
            qkv, (l == 0) ? bias : (const u16*)nullptr, attb);
        // Wo projection + residual: h2 = h + attb @ Wo[l]
        gemm_kernel<0><<<dim3(256 / GBN, MROWS / GBM), 256, 0, stream>>>(
            attb, 256, Wo + (size_t)l * 256 * 256, 256,
            nullptr, nullptr, nullptr, 0, h2, 256,
            nullptr, 0, h, 256, 256);
        zero_stats_kernel<<<1, 256, 0, stream>>>(stats);
        bn_stats_kernel<<<64, 256, 0, stream>>>(h2, stats);
        bn_apply_kernel<<<1024, 256, 0, stream>>>(h2, h, stats, bn1g + l * 256, bn1b + l * 256);
        // FF1: relu(h @ W1 + b1)
        gemm_kernel<0><<<dim3(512 / GBN, MROWS / GBM), 256, 0, stream>>>(
            h, 256, ffW1 + (size_t)l * 256 * 512, 512,
            nullptr, nullptr, nullptr, 0, ff, 512,
            ffb1 + l * 512, 1, nullptr, 0, 256);
        // FF2 + bias + residual: h2 = h + ff @ W2 + b2
        gemm_kernel<0><<<dim3(256 / GBN, MROWS / GBM), 256, 0, stream>>>(
            ff, 512, ffW2 + (size_t)l * 512 * 256, 256,
            nullptr, nullptr, nullptr, 0, h2, 256,
            ffb2 + l * 256, 0, h, 256, 512);
        zero_stats_kernel<<<1, 256, 0, stream>>>(stats);
        bn_stats_kernel<<<64, 256, 0, stream>>>(h2, stats);
        bn_apply_kernel<<<1024, 256, 0, stream>>>(
            h2, (l == 2) ? outh : h, stats, bn2g + l * 256, bn2b + l * 256);
    }
    graph_embed_kernel<<<BB, 256, 0, stream>>>(outh, outg);
}

// Round 8
// 779.659 us; speedup vs baseline: 1.0603x; 1.0603x over previous
//
#include <hip/hip_runtime.h>

// Shapes (fixed per reference)
#define BB    16
#define NNN   512
#define DDIM  256
#define HH    8
#define DKK   32
#define FFF   512
#define MROWS 8192   // B*N
#define LUTN  4096

using u16    = unsigned short;
using bf16x8 = __attribute__((ext_vector_type(8))) short;
using f32x4  = __attribute__((ext_vector_type(4))) float;

__device__ __forceinline__ float bf2f(u16 u) { return __uint_as_float(((unsigned)u) << 16); }
__device__ __forceinline__ u16 f2bf(float f) {
    unsigned u = __float_as_uint(f);
    return (u16)((u + 0x7fffu + ((u >> 16) & 1u)) >> 16);  // RNE
}

// ---------------------------------------------------------------------------
// h = x @ init_W + init_b   (x: (8192,2), W: (2,256))
__global__ __launch_bounds__(256) void init_embed_kernel(
    const float* __restrict__ x, const float* __restrict__ W,
    const float* __restrict__ b, float* __restrict__ h)
{
    size_t row = blockIdx.x;
    int c = threadIdx.x;
    float x0 = x[row * 2 + 0], x1 = x[row * 2 + 1];
    h[row * DDIM + c] = x0 * W[c] + x1 * W[DDIM + c] + b[c];
}

// ---------------------------------------------------------------------------
// Edge MLP is a scalar->R^8 piecewise-linear function: build a LUT once.
__global__ __launch_bounds__(256) void build_lut_kernel(
    const float* __restrict__ eW1, const float* __restrict__ eb1,
    const float* __restrict__ eW2, const float* __restrict__ eb2,
    const float* __restrict__ eW3, const float* __restrict__ eb3,
    float* __restrict__ lut)  // (LUTN+1) x 8
{
    int i = blockIdx.x * 256 + threadIdx.x;
    if (i > LUTN) return;
    float e = (float)i * (1.0f / LUTN);
    float t1[16], t2[16];
    #pragma unroll
    for (int a = 0; a < 16; ++a) t1[a] = fmaxf(e * eW1[a] + eb1[a], 0.0f);
    #pragma unroll
    for (int j = 0; j < 16; ++j) {
        float s = eb2[j];
        #pragma unroll
        for (int a = 0; a < 16; ++a) s += t1[a] * eW2[a * 16 + j];
        t2[j] = fmaxf(s, 0.0f);
    }
    #pragma unroll
    for (int hd = 0; hd < 8; ++hd) {
        float s = eb3[hd];
        #pragma unroll
        for (int j = 0; j < 16; ++j) s += t2[j] * eW3[j * 8 + hd];
        lut[(size_t)i * 8 + hd] = s;
    }
}

// bias[hd][b][i][j] (bf16) = lerp(LUT, edge[b,i,j])
__global__ __launch_bounds__(256) void edge_bias_kernel(
    const float* __restrict__ edge, const float* __restrict__ lut,
    u16* __restrict__ bout)
{
    size_t idx = (size_t)blockIdx.x * 256 + threadIdx.x;  // over B*N*N = 4,194,304
    float e = edge[idx];
    float f = e * (float)LUTN;
    f = fminf(fmaxf(f, 0.0f), (float)LUTN - 0.0001f);
    int i0 = (int)f;
    float fr = f - (float)i0;
    const float4* r = (const float4*)(lut + (size_t)i0 * 8);
    float4 a0 = r[0], a1 = r[1], b0 = r[2], b1 = r[3];  // row i0, row i0+1
    float o[8];
    o[0] = a0.x + fr * (b0.x - a0.x);
    o[1] = a0.y + fr * (b0.y - a0.y);
    o[2] = a0.z + fr * (b0.z - a0.z);
    o[3] = a0.w + fr * (b0.w - a0.w);
    o[4] = a1.x + fr * (b1.x - a1.x);
    o[5] = a1.y + fr * (b1.y - a1.y);
    o[6] = a1.z + fr * (b1.z - a1.z);
    o[7] = a1.w + fr * (b1.w - a1.w);
    #pragma unroll
    for (int hd = 0; hd < 8; ++hd)
        bout[(size_t)hd * (size_t)BB * NNN * NNN + idx] = f2bf(o[hd]);
}

// ---------------------------------------------------------------------------
// Split-bf16 MFMA GEMM (f32-accurate): A = Ah + Al, B = Bh + Bl (bf16 pairs);
// C = Ah*Bh + Ah*Bl + Al*Bh  (error ~2^-18, f32-equivalent).
#define GBM 128
#define GBN 64
#define GBK 32
#define LPAD 40   // u16 elems per LDS row (32 + 8 pad, keeps 16B alignment)

template <int BMODE>  // 0: plain row-major B (ldb); 1: QKV-packed weights
__global__ __launch_bounds__(256) void gemm_kernel(
    const float* __restrict__ A, int lda,
    const float* __restrict__ Bp, int ldb,
    const float* __restrict__ Wq, const float* __restrict__ Wk,
    const float* __restrict__ Wv, int layer,
    float* __restrict__ C, int ldc,
    const float* __restrict__ bias, int relu,
    const float* __restrict__ res, int ldr,
    int K)
{
    __shared__ u16 Ash[GBM][LPAD];
    __shared__ u16 Asl[GBM][LPAD];
    __shared__ u16 Bsh[GBN][LPAD];
    __shared__ u16 Bsl[GBN][LPAD];
    int m0 = blockIdx.y * GBM;
    int n0 = blockIdx.x * GBN;
    int tid = threadIdx.x;
    int lid = tid & 63, wid = tid >> 6;
    int wm = wid >> 1, wn = wid & 1;
    int l15 = lid & 15, l4 = lid >> 4;

    f32x4 acc[4][2] = {};

    for (int k0 = 0; k0 < K; k0 += GBK) {
        // stage A: 128x32 f32 -> hi/lo bf16
        #pragma unroll
        for (int j = 0; j < 4; ++j) {
            int idx = tid + 256 * j;           // 1024 float4s
            int row = idx >> 3, k4 = idx & 7;
            float4 v = *(const float4*)(A + (size_t)(m0 + row) * lda + k0 + k4 * 4);
            ushort4 wh, wl;
            wh.x = f2bf(v.x); wl.x = f2bf(v.x - bf2f(wh.x));
            wh.y = f2bf(v.y); wl.y = f2bf(v.y - bf2f(wh.y));
            wh.z = f2bf(v.z); wl.z = f2bf(v.z - bf2f(wh.z));
            wh.w = f2bf(v.w); wl.w = f2bf(v.w - bf2f(wh.w));
            *(ushort4*)&Ash[row][k4 * 4] = wh;
            *(ushort4*)&Asl[row][k4 * 4] = wl;
        }
        // stage B transposed: Bs[n][k]
        #pragma unroll
        for (int j = 0; j < 8; ++j) {
            int idx = tid + 256 * j;           // 2048 elems (32k x 64n)
            int kk = idx >> 6, nn = idx & 63;
            int gk = k0 + kk, gn = n0 + nn;
            float v;
            if (BMODE == 0) {
                v = Bp[(size_t)gk * ldb + gn];
            } else {
                int mat = gn >> 8, c8 = gn & 255, hd = c8 >> 5, dk = c8 & 31;
                const float* Wsel = (mat == 0) ? Wq : ((mat == 1) ? Wk : Wv);
                v = Wsel[(((size_t)layer * HH + hd) * DDIM + gk) * DKK + dk];
            }
            u16 hh = f2bf(v);
            Bsh[nn][kk] = hh;
            Bsl[nn][kk] = f2bf(v - bf2f(hh));
        }
        __syncthreads();
        bf16x8 afh[4], afl[4], bfh[2], bfl[2];
        #pragma unroll
        for (int mi = 0; mi < 4; ++mi) {
            afh[mi] = *(const bf16x8*)&Ash[wm * 64 + mi * 16 + l15][l4 * 8];
            afl[mi] = *(const bf16x8*)&Asl[wm * 64 + mi * 16 + l15][l4 * 8];
        }
        #pragma unroll
        for (int ni = 0; ni < 2; ++ni) {
            bfh[ni] = *(const bf16x8*)&Bsh[wn * 32 + ni * 16 + l15][l4 * 8];
            bfl[ni] = *(const bf16x8*)&Bsl[wn * 32 + ni * 16 + l15][l4 * 8];
        }
        #pragma unroll
        for (int mi = 0; mi < 4; ++mi)
            #pragma unroll
            for (int ni = 0; ni < 2; ++ni) {
                acc[mi][ni] = __builtin_amdgcn_mfma_f32_16x16x32_bf16(
                    afh[mi], bfh[ni], acc[mi][ni], 0, 0, 0);
                acc[mi][ni] = __builtin_amdgcn_mfma_f32_16x16x32_bf16(
                    afh[mi], bfl[ni], acc[mi][ni], 0, 0, 0);
                acc[mi][ni] = __builtin_amdgcn_mfma_f32_16x16x32_bf16(
                    afl[mi], bfh[ni], acc[mi][ni], 0, 0, 0);
            }
        __syncthreads();
    }
    // epilogue
    #pragma unroll
    for (int mi = 0; mi < 4; ++mi) {
        #pragma unroll
        for (int ni = 0; ni < 2; ++ni) {
            #pragma unroll
            for (int r = 0; r < 4; ++r) {
                int row = m0 + wm * 64 + mi * 16 + l4 * 4 + r;
                int col = n0 + wn * 32 + ni * 16 + l15;
                float v = acc[mi][ni][r];
                if (bias) v += bias[col];
                if (relu) v = fmaxf(v, 0.0f);
                if (res)  v += res[(size_t)row * ldr + col];
                C[(size_t)row * ldc + col] = v;
            }
        }
    }
}

// ---------------------------------------------------------------------------
// MFMA fused attention v2: 8 waves, 128 q-rows/block, grid 512 (XCD-swizzled).
// K staged ONCE as hi+lo buffers (no restage); V transposed; PV kv-chunked
// (4 x 128) through a small per-wave P buffer (no barriers needed: per-wave
// LDS RAW is ordered by lgkmcnt within the wave).
// Scores S = Qh·Kh + Ql·Kh + Qh·Kl (~f32 exact). Softmax in C-frags.
__global__ __launch_bounds__(512, 2) void attn_mfma_kernel(
    const float* __restrict__ qkv, const u16* __restrict__ bias,
    float* __restrict__ att)
{
    __shared__ u16 Ksh[512][32];      // K hi [n][k]        32 KB
    __shared__ u16 Ksl[512][32];      // K lo [n][k]        32 KB
    __shared__ u16 Vt[32][520];       // V^T[dk][n] (+pad)  33.3 KB
    __shared__ u16 Pw[8][16][136];    // per-wave P chunk   34 KB
    int wg = blockIdx.x;
    int logical = (wg & 7) * 64 + (wg >> 3);   // XCD swizzle: qtile-sharers same XCD
    int qt = logical & 3, hd = (logical >> 2) & 7, b = logical >> 5;
    int tid = threadIdx.x, lid = tid & 63, w = tid >> 6;
    int l15 = lid & 15, l4 = lid >> 4;   // l4 in 0..3

    const float* base = qkv + (size_t)b * 512 * 768;
    // stage K (hi+lo from one read) and V
    for (int idx = tid; idx < 512 * 32; idx += 512) {
        int n = idx >> 5, k = idx & 31;
        float kv = base[(size_t)n * 768 + 256 + hd * 32 + k];
        u16 kh = f2bf(kv);
        Ksh[n][k] = kh;
        Ksl[n][k] = f2bf(kv - bf2f(kh));
        Vt[k][n] = f2bf(base[(size_t)n * 768 + 512 + hd * 32 + k]);
    }
    __syncthreads();

    int qw0 = qt * 128 + w * 16;
    // Q A-frags hi/lo: row = l15, k = l4*8 + j
    bf16x8 afh, afl;
    {
        const float* qrow = base + (size_t)(qw0 + l15) * 768 + hd * 32 + l4 * 8;
        u16 th[8], tl[8];
        #pragma unroll
        for (int j = 0; j < 8; ++j) {
            float v = qrow[j];
            th[j] = f2bf(v);
            tl[j] = f2bf(v - bf2f(th[j]));
        }
        afh = *(bf16x8*)th;
        afl = *(bf16x8*)tl;
    }

    // scores: S(16 x 512) = Qh·Kh + Ql·Kh + Qh·Kl over 32 col-tiles
    f32x4 acc[32];
    #pragma unroll
    for (int ct = 0; ct < 32; ++ct) {
        bf16x8 bh = *(const bf16x8*)&Ksh[ct * 16 + l15][l4 * 8];
        bf16x8 bl = *(const bf16x8*)&Ksl[ct * 16 + l15][l4 * 8];
        f32x4 z = {0.0f, 0.0f, 0.0f, 0.0f};
        z = __builtin_amdgcn_mfma_f32_16x16x32_bf16(afh, bh, z, 0, 0, 0);
        z = __builtin_amdgcn_mfma_f32_16x16x32_bf16(afl, bh, z, 0, 0, 0);
        acc[ct] = __builtin_amdgcn_mfma_f32_16x16x32_bf16(afh, bl, z, 0, 0, 0);
    }

    const float scale = 0.17677669529663687f;  // 1/sqrt(32)
    if (bias) {
        size_t brow = (((size_t)hd * BB + b) * NNN + qw0 + l4 * 4) * NNN + l15;
        #pragma unroll
        for (int ct = 0; ct < 32; ++ct)
            #pragma unroll
            for (int r = 0; r < 4; ++r)
                acc[ct][r] = acc[ct][r] * scale +
                             bf2f(bias[brow + (size_t)r * NNN + ct * 16]);
    } else {
        #pragma unroll
        for (int ct = 0; ct < 32; ++ct)
            #pragma unroll
            for (int r = 0; r < 4; ++r)
                acc[ct][r] *= scale;
    }

    // in-fragment softmax per row (rows = qw0 + l4*4 + r; columns over ct & l15)
    float linv[4];
    #pragma unroll
    for (int r = 0; r < 4; ++r) {
        float m = acc[0][r];
        #pragma unroll
        for (int ct = 1; ct < 32; ++ct) m = fmaxf(m, acc[ct][r]);
        #pragma unroll
        for (int msk = 1; msk < 16; msk <<= 1) m = fmaxf(m, __shfl_xor(m, msk));
        float lsum = 0.0f;
        #pragma unroll
        for (int ct = 0; ct < 32; ++ct) {
            float p = __expf(acc[ct][r] - m);
            acc[ct][r] = p;
            lsum += p;
        }
        #pragma unroll
        for (int msk = 1; msk < 16; msk <<= 1) lsum += __shfl_xor(lsum, msk);
        linv[r] = 1.0f / lsum;
    }

    // PV in 4 kv-chunks of 128 through per-wave P buffer (no barriers)
    f32x4 oacc[2] = {};
    for (int cc = 0; cc < 4; ++cc) {
        #pragma unroll
        for (int ct8 = 0; ct8 < 8; ++ct8) {
            int ct = cc * 8 + ct8;
            #pragma unroll
            for (int r = 0; r < 4; ++r)
                Pw[w][l4 * 4 + r][ct8 * 16 + l15] = f2bf(acc[ct][r]);
        }
        #pragma unroll
        for (int ks = 0; ks < 4; ++ks) {
            bf16x8 pa = *(const bf16x8*)&Pw[w][l15][ks * 32 + l4 * 8];
            #pragma unroll
            for (int ct2 = 0; ct2 < 2; ++ct2) {
                bf16x8 vb = *(const bf16x8*)&Vt[ct2 * 16 + l15][cc * 128 + ks * 32 + l4 * 8];
                oacc[ct2] = __builtin_amdgcn_mfma_f32_16x16x32_bf16(pa, vb, oacc[ct2], 0, 0, 0);
            }
        }
    }
    // epilogue: col = hd*32 + ct2*16 + l15, row = qw0 + l4*4 + r, scale by linv[r]
    #pragma unroll
    for (int ct2 = 0; ct2 < 2; ++ct2)
        #pragma unroll
        for (int r = 0; r < 4; ++r)
            att[((size_t)b * NNN + qw0 + l4 * 4 + r) * DDIM + hd * 32 + ct2 * 16 + l15] =
                oacc[ct2][r] * linv[r];
}

// ---------------------------------------------------------------------------
__global__ void zero_stats_kernel(float* stats)
{
    stats[threadIdx.x] = 0.0f;
    stats[256 + threadIdx.x] = 0.0f;
}

__global__ __launch_bounds__(256) void bn_stats_kernel(
    const float* __restrict__ X, float* __restrict__ stats)
{
    int c = threadIdx.x;
    size_t r0 = (size_t)blockIdx.x * 32;
    float s = 0.0f, ss = 0.0f;
    for (int r = 0; r < 32; ++r) {
        float v = X[(r0 + r) * DDIM + c];
        s += v; ss += v * v;
    }
    atomicAdd(&stats[c], s);
    atomicAdd(&stats[256 + c], ss);
}

__global__ __launch_bounds__(256) void bn_apply_kernel(
    const float* __restrict__ X, float* __restrict__ Y,
    const float* __restrict__ stats,
    const float* __restrict__ g, const float* __restrict__ bb)
{
    int c = threadIdx.x;
    float mean = stats[c] * (1.0f / MROWS);
    float var  = stats[256 + c] * (1.0f / MROWS) - mean * mean;
    float inv  = rsqrtf(var + 1e-5f);
    float gg = g[c] * inv;
    float off = bb[c] - mean * gg;
    size_t r0 = (size_t)blockIdx.x * 8;
    #pragma unroll
    for (int r = 0; r < 8; ++r) {
        size_t o = (r0 + r) * DDIM + c;
        Y[o] = X[o] * gg + off;
    }
}

__global__ __launch_bounds__(256) void graph_embed_kernel(
    const float* __restrict__ outh, float* __restrict__ outg)
{
    int c = threadIdx.x, b = blockIdx.x;
    float s = 0.0f;
    for (int n = 0; n < NNN; ++n)
        s += outh[((size_t)b * NNN + n) * DDIM + c];
    outg[b * DDIM + c] = s * (1.0f / NNN);
}

// ---------------------------------------------------------------------------
extern "C" void kernel_launch(void* const* d_in, const int* in_sizes, int n_in,
                              void* d_out, int out_size, void* d_ws, size_t ws_size,
                              hipStream_t stream)
{
    const float* x     = (const float*)d_in[0];
    const float* edge  = (const float*)d_in[1];
    const float* initW = (const float*)d_in[2];
    const float* initb = (const float*)d_in[3];
    const float* Wq    = (const float*)d_in[4];
    const float* Wk    = (const float*)d_in[5];
    const float* Wv    = (const float*)d_in[6];
    const float* Wo    = (const float*)d_in[7];
    const float* eW1   = (const float*)d_in[8];
    const float* eb1   = (const float*)d_in[9];
    const float* eW2   = (const float*)d_in[10];
    const float* eb2   = (const float*)d_in[11];
    const float* eW3   = (const float*)d_in[12];
    const float* eb3   = (const float*)d_in[13];
    const float* bn1g  = (const float*)d_in[14];
    const float* bn1b  = (const float*)d_in[15];
    const float* ffW1  = (const float*)d_in[16];
    const float* ffb1  = (const float*)d_in[17];
    const float* ffW2  = (const float*)d_in[18];
    const float* ffb2  = (const float*)d_in[19];
    const float* bn2g  = (const float*)d_in[20];
    const float* bn2b  = (const float*)d_in[21];

    char* ws = (char*)d_ws;
    float* h     = (float*)(ws);                           //  8 MB
    float* h2    = (float*)(ws + ((size_t)8 << 20));       //  8 MB
    float* qkv   = (float*)(ws + ((size_t)16 << 20));      // 24 MB
    float* attb  = (float*)(ws + ((size_t)40 << 20));      //  8 MB
    float* ff    = (float*)(ws + ((size_t)48 << 20));      // 16 MB
    float* stats = (float*)(ws + ((size_t)64 << 20));      //  2 KB
    float* lut   = (float*)(ws + ((size_t)64 << 20) + 4096); // ~128 KB
    u16*   bias  = (u16*)  (ws + ((size_t)65 << 20));      // 64 MB
    float* outh  = (float*)d_out;
    float* outg  = outh + (size_t)MROWS * DDIM;

    init_embed_kernel<<<MROWS, 256, 0, stream>>>(x, initW, initb, h);
    build_lut_kernel<<<17, 256, 0, stream>>>(eW1, eb1, eW2, eb2, eW3, eb3, lut);
    edge_bias_kernel<<<(BB * NNN * NNN) / 256, 256, 0, stream>>>(edge, lut, bias);

    for (int l = 0; l < 3; ++l) {
        // QKV projection: (8192x256) @ packed (256x768)
        gemm_kernel<1><<<dim3(768 / GBN, MROWS / GBM), 256, 0, stream>>>(
            h, 256, nullptr, 0, Wq, Wk, Wv, l, qkv, 768,
            nullptr, 0, nullptr, 0, 256);
        // fused MFMA attention (8-wave, XCD-swizzled)
        attn_mfma_kernel<<<512, 512, 0, stream>>>(
            qkv, (l == 0) ? bias : (const u16*)nullptr, attb);
        // Wo projection + residual: h2 = h + attb @ Wo[l]
        gemm_kernel<0><<<dim3(256 / GBN, MROWS / GBM), 256, 0, stream>>>(
            attb, 256, Wo + (size_t)l * 256 * 256, 256,
            nullptr, nullptr, nullptr, 0, h2, 256,
            nullptr, 0, h, 256, 256);
        zero_stats_kernel<<<1, 256, 0, stream>>>(stats);
        bn_stats_kernel<<<256, 256, 0, stream>>>(h2, stats);
        bn_apply_kernel<<<1024, 256, 0, stream>>>(h2, h, stats, bn1g + l * 256, bn1b + l * 256);
        // FF1: relu(h @ W1 + b1)
        gemm_kernel<0><<<dim3(512 / GBN, MROWS / GBM), 256, 0, stream>>>(
            h, 256, ffW1 + (size_t)l * 256 * 512, 512,
            nullptr, nullptr, nullptr, 0, ff, 512,
            ffb1 + l * 512, 1, nullptr, 0, 256);
        // FF2 + bias + residual: h2 = h + ff @ W2 + b2
        gemm_kernel<0><<<dim3(256 / GBN, MROWS / GBM), 256, 0, stream>>>(
            ff, 512, ffW2 + (size_t)l * 512 * 256, 256,
            nullptr, nullptr, nullptr, 0, h2, 256,
            ffb2 + l * 256, 0, h, 256, 512);
        zero_stats_kernel<<<1, 256, 0, stream>>>(stats);
        bn_stats_kernel<<<256, 256, 0, stream>>>(h2, stats);
        bn_apply_kernel<<<1024, 256, 0, stream>>>(
            h2, (l == 2) ? outh : h, stats, bn2g + l * 256, bn2b + l * 256);
    }
    graph_embed_kernel<<<BB, 256, 0, stream>>>(outh, outg);
}

// Round 9
// 758.999 us; speedup vs baseline: 1.0891x; 1.0272x over previous
//
#include <hip/hip_runtime.h>

// Shapes (fixed per reference)
#define BB    16
#define NNN   512
#define DDIM  256
#define HH    8
#define DKK   32
#define FFF   512
#define MROWS 8192   // B*N
#define LUTN  4096

using u16    = unsigned short;
using bf16x8 = __attribute__((ext_vector_type(8))) short;
using f32x4  = __attribute__((ext_vector_type(4))) float;

__device__ __forceinline__ float bf2f(u16 u) { return __uint_as_float(((unsigned)u) << 16); }
__device__ __forceinline__ u16 f2bf(float f) {
    unsigned u = __float_as_uint(f);
    return (u16)((u + 0x7fffu + ((u >> 16) & 1u)) >> 16);  // RNE
}

// ---------------------------------------------------------------------------
// h = x @ init_W + init_b ; also emit h_hi/h_lo bf16 split
__global__ __launch_bounds__(256) void init_embed_kernel(
    const float* __restrict__ x, const float* __restrict__ W,
    const float* __restrict__ b, float* __restrict__ h,
    u16* __restrict__ hhi, u16* __restrict__ hlo)
{
    size_t row = blockIdx.x;
    int c = threadIdx.x;
    float x0 = x[row * 2 + 0], x1 = x[row * 2 + 1];
    float v = x0 * W[c] + x1 * W[DDIM + c] + b[c];
    size_t o = row * DDIM + c;
    h[o] = v;
    u16 hv = f2bf(v);
    hhi[o] = hv;
    hlo[o] = f2bf(v - bf2f(hv));
}

// ---------------------------------------------------------------------------
// One-shot weight transpose + hi/lo split.  Per layer (u16-elem offsets within
// a 1048576-elem layer block):
//   QKVt [768][256]  hi@0       lo@196608
//   Wot  [256][256]  hi@393216  lo@458752
//   FF1t [512][256]  hi@524288  lo@655360
//   FF2t [256][512]  hi@786432  lo@917504
#define WT_LSTR 1048576
__global__ __launch_bounds__(256) void wsplit_kernel(
    const float* __restrict__ Wq, const float* __restrict__ Wk,
    const float* __restrict__ Wv, const float* __restrict__ Wo,
    const float* __restrict__ ffW1, const float* __restrict__ ffW2,
    u16* __restrict__ Wt)
{
    int fid = blockIdx.x * 256 + threadIdx.x;   // 3 * 524288 total
    int l = fid >> 19, r = fid & 524287;
    u16* base = Wt + (size_t)l * WT_LSTR;
    float v; int off_hi, off_lo;
    if (r < 196608) {                 // QKVt: n = r>>8, k = r&255
        int n = r >> 8, k = r & 255;
        int mat = n >> 8, hd = (n & 255) >> 5, dk = n & 31;
        const float* Wsel = (mat == 0) ? Wq : ((mat == 1) ? Wk : Wv);
        v = Wsel[(((size_t)l * HH + hd) * DDIM + k) * DKK + dk];
        off_hi = r; off_lo = r + 196608;
    } else if (r < 262144) {          // Wot
        int r2 = r - 196608;
        int n = r2 >> 8, k = r2 & 255;
        int hd = k >> 5, dk = k & 31;
        v = Wo[(((size_t)l * HH + hd) * DKK + dk) * DDIM + n];
        off_hi = 393216 + r2; off_lo = 458752 + r2;
    } else if (r < 393216) {          // FF1t
        int r3 = r - 262144;
        int n = r3 >> 8, k = r3 & 255;
        v = ffW1[((size_t)l * DDIM + k) * FFF + n];
        off_hi = 524288 + r3; off_lo = 655360 + r3;
    } else {                          // FF2t
        int r4 = r - 393216;
        int n = r4 >> 9, k = r4 & 511;
        v = ffW2[((size_t)l * FFF + k) * DDIM + n];
        off_hi = 786432 + r4; off_lo = 917504 + r4;
    }
    u16 hv = f2bf(v);
    base[off_hi] = hv;
    base[off_lo] = f2bf(v - bf2f(hv));
}

// ---------------------------------------------------------------------------
// Edge MLP is a scalar->R^8 piecewise-linear function: build a LUT once.
__global__ __launch_bounds__(256) void build_lut_kernel(
    const float* __restrict__ eW1, const float* __restrict__ eb1,
    const float* __restrict__ eW2, const float* __restrict__ eb2,
    const float* __restrict__ eW3, const float* __restrict__ eb3,
    float* __restrict__ lut)  // (LUTN+1) x 8
{
    int i = blockIdx.x * 256 + threadIdx.x;
    if (i > LUTN) return;
    float e = (float)i * (1.0f / LUTN);
    float t1[16], t2[16];
    #pragma unroll
    for (int a = 0; a < 16; ++a) t1[a] = fmaxf(e * eW1[a] + eb1[a], 0.0f);
    #pragma unroll
    for (int j = 0; j < 16; ++j) {
        float s = eb2[j];
        #pragma unroll
        for (int a = 0; a < 16; ++a) s += t1[a] * eW2[a * 16 + j];
        t2[j] = fmaxf(s, 0.0f);
    }
    #pragma unroll
    for (int hd = 0; hd < 8; ++hd) {
        float s = eb3[hd];
        #pragma unroll
        for (int j = 0; j < 16; ++j) s += t2[j] * eW3[j * 8 + hd];
        lut[(size_t)i * 8 + hd] = s;
    }
}

// bias[hd][b][i][j] (bf16) = lerp(LUT, edge[b,i,j])
__global__ __launch_bounds__(256) void edge_bias_kernel(
    const float* __restrict__ edge, const float* __restrict__ lut,
    u16* __restrict__ bout)
{
    size_t idx = (size_t)blockIdx.x * 256 + threadIdx.x;
    float e = edge[idx];
    float f = e * (float)LUTN;
    f = fminf(fmaxf(f, 0.0f), (float)LUTN - 0.0001f);
    int i0 = (int)f;
    float fr = f - (float)i0;
    const float4* r = (const float4*)(lut + (size_t)i0 * 8);
    float4 a0 = r[0], a1 = r[1], b0 = r[2], b1 = r[3];
    float o[8];
    o[0] = a0.x + fr * (b0.x - a0.x);
    o[1] = a0.y + fr * (b0.y - a0.y);
    o[2] = a0.z + fr * (b0.z - a0.z);
    o[3] = a0.w + fr * (b0.w - a0.w);
    o[4] = a1.x + fr * (b1.x - a1.x);
    o[5] = a1.y + fr * (b1.y - a1.y);
    o[6] = a1.z + fr * (b1.z - a1.z);
    o[7] = a1.w + fr * (b1.w - a1.w);
    #pragma unroll
    for (int hd = 0; hd < 8; ++hd)
        bout[(size_t)hd * (size_t)BB * NNN * NNN + idx] = f2bf(o[hd]);
}

// ---------------------------------------------------------------------------
// GEMM v2: inputs PRE-SPLIT bf16 (A [M][K] hi/lo, Bt [N][K] hi/lo transposed).
// C = Ah*Bh + Ah*Bl + Al*Bh (f32-equivalent). Tile 128x64, BK=64, 4 waves.
// A staged in padded LDS; B frags loaded直接 from L2 (weights are resident).
// Epilogue: optional f32 out, optional split bf16 out, bias/relu/residual.
__global__ __launch_bounds__(256, 4) void gemm2_kernel(
    const u16* __restrict__ Ah_g, const u16* __restrict__ Al_g, int K,
    const u16* __restrict__ Bth, const u16* __restrict__ Btl, int N,
    float* __restrict__ Cf,
    u16* __restrict__ Chi, u16* __restrict__ Clo,
    const float* __restrict__ bias, int relu,
    const float* __restrict__ res)
{
    __shared__ __align__(16) u16 Ah[128][72];   // 144B rows: 16B-aligned, 2-way max
    __shared__ __align__(16) u16 Al[128][72];
    int m0 = blockIdx.y * 128, n0 = blockIdx.x * 64;
    int tid = threadIdx.x, lid = tid & 63, wid = tid >> 6;
    int wm = wid >> 1, wn = wid & 1;
    int l15 = lid & 15, l4 = lid >> 4;

    f32x4 acc[4][2] = {};

    for (int k0 = 0; k0 < K; k0 += 64) {
        // stage A hi/lo: 128x64 bf16 each (pure copies, no conversion)
        #pragma unroll
        for (int j = 0; j < 4; ++j) {
            int c = tid + 256 * j;          // 1024 chunks of 8 elems
            int row = c >> 3, col8 = c & 7;
            bf16x8 vh = *(const bf16x8*)&Ah_g[(size_t)(m0 + row) * K + k0 + col8 * 8];
            bf16x8 vl = *(const bf16x8*)&Al_g[(size_t)(m0 + row) * K + k0 + col8 * 8];
            *(bf16x8*)&Ah[row][col8 * 8] = vh;
            *(bf16x8*)&Al[row][col8 * 8] = vl;
        }
        __syncthreads();
        #pragma unroll
        for (int ks = 0; ks < 2; ++ks) {
            int ko = ks * 32;
            bf16x8 afh[4], afl[4], bfh[2], bfl[2];
            #pragma unroll
            for (int mi = 0; mi < 4; ++mi) {
                afh[mi] = *(const bf16x8*)&Ah[wm * 64 + mi * 16 + l15][ko + l4 * 8];
                afl[mi] = *(const bf16x8*)&Al[wm * 64 + mi * 16 + l15][ko + l4 * 8];
            }
            #pragma unroll
            for (int ni = 0; ni < 2; ++ni) {
                size_t brow = (size_t)(n0 + wn * 32 + ni * 16 + l15) * K + k0 + ko + l4 * 8;
                bfh[ni] = *(const bf16x8*)&Bth[brow];
                bfl[ni] = *(const bf16x8*)&Btl[brow];
            }
            #pragma unroll
            for (int mi = 0; mi < 4; ++mi)
                #pragma unroll
                for (int ni = 0; ni < 2; ++ni) {
                    acc[mi][ni] = __builtin_amdgcn_mfma_f32_16x16x32_bf16(
                        afh[mi], bfh[ni], acc[mi][ni], 0, 0, 0);
                    acc[mi][ni] = __builtin_amdgcn_mfma_f32_16x16x32_bf16(
                        afh[mi], bfl[ni], acc[mi][ni], 0, 0, 0);
                    acc[mi][ni] = __builtin_amdgcn_mfma_f32_16x16x32_bf16(
                        afl[mi], bfh[ni], acc[mi][ni], 0, 0, 0);
                }
        }
        __syncthreads();
    }
    // epilogue
    #pragma unroll
    for (int mi = 0; mi < 4; ++mi) {
        #pragma unroll
        for (int ni = 0; ni < 2; ++ni) {
            #pragma unroll
            for (int r = 0; r < 4; ++r) {
                int row = m0 + wm * 64 + mi * 16 + l4 * 4 + r;
                int col = n0 + wn * 32 + ni * 16 + l15;
                float v = acc[mi][ni][r];
                if (bias) v += bias[col];
                if (relu) v = fmaxf(v, 0.0f);
                if (res)  v += res[(size_t)row * N + col];
                size_t o = (size_t)row * N + col;
                if (Cf) Cf[o] = v;
                if (Chi) {
                    u16 hv = f2bf(v);
                    Chi[o] = hv;
                    Clo[o] = f2bf(v - bf2f(hv));
                }
            }
        }
    }
}

// ---------------------------------------------------------------------------
// MFMA fused attention v3: consumes pre-split bf16 qkv (hi/lo), emits split
// attb. 8 waves, 128 q-rows/block, grid 512 XCD-swizzled. K hi in padded LDS;
// K lo in a buffer UNIONED with the P chunk buffer (lo only used during
// scores; barrier separates). V hi transposed. PV in 8 kv-chunks of 64.
__global__ __launch_bounds__(512, 2) void attn_mfma_kernel(
    const u16* __restrict__ qkv_hi, const u16* __restrict__ qkv_lo,
    const u16* __restrict__ bias,
    u16* __restrict__ attb_hi, u16* __restrict__ attb_lo)
{
    __shared__ __align__(16) u16 Ksh[512][40];   // 80B rows: 16B-aligned, 2-way max
    __shared__ __align__(16) u16 UB[512 * 40];   // union: Ksl[512][40] | Pw[8][16][72]
    __shared__ __align__(16) u16 Vt[32][520];
    int wg = blockIdx.x;
    int logical = (wg & 7) * 64 + (wg >> 3);   // bijective (512 % 8 == 0)
    int qt = logical & 3, hd = (logical >> 2) & 7, b = logical >> 5;
    int tid = threadIdx.x, lid = tid & 63, w = tid >> 6;
    int l15 = lid & 15, l4 = lid >> 4;

    const u16* baseh = qkv_hi + (size_t)b * 512 * 768;
    const u16* basel = qkv_lo + (size_t)b * 512 * 768;
    u16 (*Ksl)[40] = (u16(*)[40])UB;

    // stage K hi/lo + V hi (pure bf16 copies, coalesced ushort4)
    for (int q4 = tid; q4 < 512 * 8; q4 += 512) {
        int n = q4 >> 3, c4 = q4 & 7;
        ushort4 kh = *(const ushort4*)&baseh[(size_t)n * 768 + 256 + hd * 32 + c4 * 4];
        ushort4 kl = *(const ushort4*)&basel[(size_t)n * 768 + 256 + hd * 32 + c4 * 4];
        ushort4 vh = *(const ushort4*)&baseh[(size_t)n * 768 + 512 + hd * 32 + c4 * 4];
        *(ushort4*)&Ksh[n][c4 * 4] = kh;
        *(ushort4*)&Ksl[n][c4 * 4] = kl;
        Vt[c4 * 4 + 0][n] = vh.x;
        Vt[c4 * 4 + 1][n] = vh.y;
        Vt[c4 * 4 + 2][n] = vh.z;
        Vt[c4 * 4 + 3][n] = vh.w;
    }
    __syncthreads();

    int qw0 = qt * 128 + w * 16;
    // Q A-frags hi/lo: direct 16B global loads (no conversion)
    bf16x8 afh = *(const bf16x8*)&baseh[(size_t)(qw0 + l15) * 768 + hd * 32 + l4 * 8];
    bf16x8 afl = *(const bf16x8*)&basel[(size_t)(qw0 + l15) * 768 + hd * 32 + l4 * 8];

    // scores: S = Qh·Kh + Ql·Kh + Qh·Kl over 32 col-tiles
    f32x4 acc[32];
    #pragma unroll
    for (int ct = 0; ct < 32; ++ct) {
        bf16x8 bh = *(const bf16x8*)&Ksh[ct * 16 + l15][l4 * 8];
        bf16x8 bl = *(const bf16x8*)&Ksl[ct * 16 + l15][l4 * 8];
        f32x4 z = {0.0f, 0.0f, 0.0f, 0.0f};
        z = __builtin_amdgcn_mfma_f32_16x16x32_bf16(afh, bh, z, 0, 0, 0);
        z = __builtin_amdgcn_mfma_f32_16x16x32_bf16(afl, bh, z, 0, 0, 0);
        acc[ct] = __builtin_amdgcn_mfma_f32_16x16x32_bf16(afh, bl, z, 0, 0, 0);
    }
    __syncthreads();   // all waves done with Ksl before Pw overwrites UB

    const float scale = 0.17677669529663687f;  // 1/sqrt(32)
    if (bias) {
        size_t brow = (((size_t)hd * BB + b) * NNN + qw0 + l4 * 4) * NNN + l15;
        #pragma unroll
        for (int ct = 0; ct < 32; ++ct)
            #pragma unroll
            for (int r = 0; r < 4; ++r)
                acc[ct][r] = acc[ct][r] * scale +
                             bf2f(bias[brow + (size_t)r * NNN + ct * 16]);
    } else {
        #pragma unroll
        for (int ct = 0; ct < 32; ++ct)
            #pragma unroll
            for (int r = 0; r < 4; ++r)
                acc[ct][r] *= scale;
    }

    // in-fragment softmax per row
    float linv[4];
    #pragma unroll
    for (int r = 0; r < 4; ++r) {
        float m = acc[0][r];
        #pragma unroll
        for (int ct = 1; ct < 32; ++ct) m = fmaxf(m, acc[ct][r]);
        #pragma unroll
        for (int msk = 1; msk < 16; msk <<= 1) m = fmaxf(m, __shfl_xor(m, msk));
        float lsum = 0.0f;
        #pragma unroll
        for (int ct = 0; ct < 32; ++ct) {
            float p = __expf(acc[ct][r] - m);
            acc[ct][r] = p;
            lsum += p;
        }
        #pragma unroll
        for (int msk = 1; msk < 16; msk <<= 1) lsum += __shfl_xor(lsum, msk);
        linv[r] = 1.0f / lsum;
    }

    // PV in 8 kv-chunks of 64 via per-wave P buffer in UB (intra-wave ordering)
    u16 (*Pw)[72] = (u16(*)[72])(UB + w * 16 * 72);
    f32x4 oacc[2] = {};
    for (int cc = 0; cc < 8; ++cc) {
        #pragma unroll
        for (int ct4 = 0; ct4 < 4; ++ct4) {
            int ct = cc * 4 + ct4;
            #pragma unroll
            for (int r = 0; r < 4; ++r)
                Pw[l4 * 4 + r][ct4 * 16 + l15] = f2bf(acc[ct][r]);
        }
        #pragma unroll
        for (int ks = 0; ks < 2; ++ks) {
            bf16x8 pa = *(const bf16x8*)&Pw[l15][ks * 32 + l4 * 8];
            #pragma unroll
            for (int ct2 = 0; ct2 < 2; ++ct2) {
                bf16x8 vb = *(const bf16x8*)&Vt[ct2 * 16 + l15][cc * 64 + ks * 32 + l4 * 8];
                oacc[ct2] = __builtin_amdgcn_mfma_f32_16x16x32_bf16(pa, vb, oacc[ct2], 0, 0, 0);
            }
        }
    }
    // epilogue: split-write attb
    #pragma unroll
    for (int ct2 = 0; ct2 < 2; ++ct2)
        #pragma unroll
        for (int r = 0; r < 4; ++r) {
            float o = oacc[ct2][r] * linv[r];
            size_t oi = ((size_t)b * NNN + qw0 + l4 * 4 + r) * DDIM + hd * 32 + ct2 * 16 + l15;
            u16 hv = f2bf(o);
            attb_hi[oi] = hv;
            attb_lo[oi] = f2bf(o - bf2f(hv));
        }
}

// ---------------------------------------------------------------------------
__global__ void zero_stats_kernel(float* stats)
{
    stats[threadIdx.x] = 0.0f;
    stats[256 + threadIdx.x] = 0.0f;
}

__global__ __launch_bounds__(256) void bn_stats_kernel(
    const float* __restrict__ X, float* __restrict__ stats)
{
    int c = threadIdx.x;
    size_t r0 = (size_t)blockIdx.x * 32;
    float s = 0.0f, ss = 0.0f;
    for (int r = 0; r < 32; ++r) {
        float v = X[(r0 + r) * DDIM + c];
        s += v; ss += v * v;
    }
    atomicAdd(&stats[c], s);
    atomicAdd(&stats[256 + c], ss);
}

__global__ __launch_bounds__(256) void bn_apply_kernel(
    const float* __restrict__ X, float* __restrict__ Y,
    u16* __restrict__ Yhi, u16* __restrict__ Ylo,
    const float* __restrict__ stats,
    const float* __restrict__ g, const float* __restrict__ bb)
{
    int c = threadIdx.x;
    float mean = stats[c] * (1.0f / MROWS);
    float var  = stats[256 + c] * (1.0f / MROWS) - mean * mean;
    float inv  = rsqrtf(var + 1e-5f);
    float gg = g[c] * inv;
    float off = bb[c] - mean * gg;
    size_t r0 = (size_t)blockIdx.x * 8;
    #pragma unroll
    for (int r = 0; r < 8; ++r) {
        size_t o = (r0 + r) * DDIM + c;
        float y = X[o] * gg + off;
        Y[o] = y;
        if (Yhi) {
            u16 hv = f2bf(y);
            Yhi[o] = hv;
            Ylo[o] = f2bf(y - bf2f(hv));
        }
    }
}

__global__ __launch_bounds__(256) void graph_embed_kernel(
    const float* __restrict__ outh, float* __restrict__ outg)
{
    int c = threadIdx.x, b = blockIdx.x;
    float s = 0.0f;
    for (int n = 0; n < NNN; ++n)
        s += outh[((size_t)b * NNN + n) * DDIM + c];
    outg[b * DDIM + c] = s * (1.0f / NNN);
}

// ---------------------------------------------------------------------------
extern "C" void kernel_launch(void* const* d_in, const int* in_sizes, int n_in,
                              void* d_out, int out_size, void* d_ws, size_t ws_size,
                              hipStream_t stream)
{
    const float* x     = (const float*)d_in[0];
    const float* edge  = (const float*)d_in[1];
    const float* initW = (const float*)d_in[2];
    const float* initb = (const float*)d_in[3];
    const float* Wq    = (const float*)d_in[4];
    const float* Wk    = (const float*)d_in[5];
    const float* Wv    = (const float*)d_in[6];
    const float* Wo    = (const float*)d_in[7];
    const float* eW1   = (const float*)d_in[8];
    const float* eb1   = (const float*)d_in[9];
    const float* eW2   = (const float*)d_in[10];
    const float* eb2   = (const float*)d_in[11];
    const float* eW3   = (const float*)d_in[12];
    const float* eb3   = (const float*)d_in[13];
    const float* bn1g  = (const float*)d_in[14];
    const float* bn1b  = (const float*)d_in[15];
    const float* ffW1  = (const float*)d_in[16];
    const float* ffb1  = (const float*)d_in[17];
    const float* ffW2  = (const float*)d_in[18];
    const float* ffb2  = (const float*)d_in[19];
    const float* bn2g  = (const float*)d_in[20];
    const float* bn2b  = (const float*)d_in[21];

    char* ws = (char*)d_ws;
    float* h      = (float*)(ws);                            //  8 MB @0
    float* h2     = (float*)(ws + ((size_t)8  << 20));       //  8 MB @8
    u16*   h_hi   = (u16*)  (ws + ((size_t)16 << 20));       //  4 MB @16 (alias attb_hi)
    u16*   h_lo   = (u16*)  (ws + ((size_t)20 << 20));       //  4 MB @20 (alias attb_lo)
    u16*   qkv_hi = (u16*)  (ws + ((size_t)24 << 20));       // 12 MB @24 (alias ff_hi 8MB)
    u16*   qkv_lo = (u16*)  (ws + ((size_t)36 << 20));       // 12 MB @36 (alias ff_lo 8MB)
    float* stats  = (float*)(ws + ((size_t)48 << 20));       //  2 KB @48
    float* lut    = (float*)(ws + ((size_t)48 << 20) + 4096);// ~131 KB
    u16*   Wt     = (u16*)  (ws + ((size_t)49 << 20));       //  6 MB @49
    u16*   bias   = (u16*)  (ws + ((size_t)56 << 20));       // 64 MB @56 (end 120 MB)
    u16*   attb_hi = h_hi;
    u16*   attb_lo = h_lo;
    u16*   ff_hi   = qkv_hi;
    u16*   ff_lo   = qkv_lo;
    float* outh  = (float*)d_out;
    float* outg  = outh + (size_t)MROWS * DDIM;

    wsplit_kernel<<<6144, 256, 0, stream>>>(Wq, Wk, Wv, Wo, ffW1, ffW2, Wt);
    init_embed_kernel<<<MROWS, 256, 0, stream>>>(x, initW, initb, h, h_hi, h_lo);
    build_lut_kernel<<<17, 256, 0, stream>>>(eW1, eb1, eW2, eb2, eW3, eb3, lut);
    edge_bias_kernel<<<(BB * NNN * NNN) / 256, 256, 0, stream>>>(edge, lut, bias);

    for (int l = 0; l < 3; ++l) {
        u16* WL = Wt + (size_t)l * WT_LSTR;
        // QKV projection -> split qkv
        gemm2_kernel<<<dim3(12, 64), 256, 0, stream>>>(
            h_hi, h_lo, 256, WL, WL + 196608, 768,
            nullptr, qkv_hi, qkv_lo, nullptr, 0, nullptr);
        // fused MFMA attention -> split attb (overwrites h_hi/h_lo region)
        attn_mfma_kernel<<<512, 512, 0, stream>>>(
            qkv_hi, qkv_lo, (l == 0) ? bias : (const u16*)nullptr, attb_hi, attb_lo);
        // Wo projection + residual: h2 = h + attb @ Wo
        gemm2_kernel<<<dim3(4, 64), 256, 0, stream>>>(
            attb_hi, attb_lo, 256, WL + 393216, WL + 458752, 256,
            h2, nullptr, nullptr, nullptr, 0, h);
        zero_stats_kernel<<<1, 256, 0, stream>>>(stats);
        bn_stats_kernel<<<256, 256, 0, stream>>>(h2, stats);
        bn_apply_kernel<<<1024, 256, 0, stream>>>(
            h2, h, h_hi, h_lo, stats, bn1g + l * 256, bn1b + l * 256);
        // FF1: relu(h @ W1 + b1) -> split ff (overwrites qkv region)
        gemm2_kernel<<<dim3(8, 64), 256, 0, stream>>>(
            h_hi, h_lo, 256, WL + 524288, WL + 655360, 512,
            nullptr, ff_hi, ff_lo, ffb1 + l * 512, 1, nullptr);
        // FF2 + bias + residual: h2 = h + ff @ W2 + b2
        gemm2_kernel<<<dim3(4, 64), 256, 0, stream>>>(
            ff_hi, ff_lo, 512, WL + 786432, WL + 917504, 256,
            h2, nullptr, nullptr, ffb2 + l * 256, 0, h);
        zero_stats_kernel<<<1, 256, 0, stream>>>(stats);
        bn_stats_kernel<<<256, 256, 0, stream>>>(h2, stats);
        if (l == 2)
            bn_apply_kernel<<<1024, 256, 0, stream>>>(
                h2, outh, nullptr, nullptr, stats, bn2g + l * 256, bn2b + l * 256);
        else
            bn_apply_kernel<<<1024, 256, 0, stream>>>(
                h2, h, h_hi, h_lo, stats, bn2g + l * 256, bn2b + l * 256);
    }
    graph_embed_kernel<<<BB, 256, 0, stream>>>(outh, outg);
}

// Round 10
// 745.930 us; speedup vs baseline: 1.1082x; 1.0175x over previous
//
#include <hip/hip_runtime.h>

// Shapes (fixed per reference)
#define BB    16
#define NNN   512
#define DDIM  256
#define HH    8
#define DKK   32
#define FFF   512
#define MROWS 8192   // B*N
#define LUTN  4096

using u16    = unsigned short;
using bf16x8 = __attribute__((ext_vector_type(8))) short;
using f32x4  = __attribute__((ext_vector_type(4))) float;

__device__ __forceinline__ float bf2f(u16 u) { return __uint_as_float(((unsigned)u) << 16); }
__device__ __forceinline__ u16 f2bf(float f) {
    unsigned u = __float_as_uint(f);
    return (u16)((u + 0x7fffu + ((u >> 16) & 1u)) >> 16);  // RNE
}

// ---------------------------------------------------------------------------
// h = x @ init_W + init_b ; also emit h_hi/h_lo bf16 split
__global__ __launch_bounds__(256) void init_embed_kernel(
    const float* __restrict__ x, const float* __restrict__ W,
    const float* __restrict__ b, float* __restrict__ h,
    u16* __restrict__ hhi, u16* __restrict__ hlo)
{
    size_t row = blockIdx.x;
    int c = threadIdx.x;
    float x0 = x[row * 2 + 0], x1 = x[row * 2 + 1];
    float v = x0 * W[c] + x1 * W[DDIM + c] + b[c];
    size_t o = row * DDIM + c;
    h[o] = v;
    u16 hv = f2bf(v);
    hhi[o] = hv;
    hlo[o] = f2bf(v - bf2f(hv));
}

// ---------------------------------------------------------------------------
// One-shot weight transpose + hi/lo split.  Per layer (u16-elem offsets within
// a 1048576-elem layer block):
//   QKVt [768][256]  hi@0       lo@196608
//   Wot  [256][256]  hi@393216  lo@458752
//   FF1t [512][256]  hi@524288  lo@655360
//   FF2t [256][512]  hi@786432  lo@917504
#define WT_LSTR 1048576
__global__ __launch_bounds__(256) void wsplit_kernel(
    const float* __restrict__ Wq, const float* __restrict__ Wk,
    const float* __restrict__ Wv, const float* __restrict__ Wo,
    const float* __restrict__ ffW1, const float* __restrict__ ffW2,
    u16* __restrict__ Wt)
{
    int fid = blockIdx.x * 256 + threadIdx.x;   // 3 * 524288 total
    int l = fid >> 19, r = fid & 524287;
    u16* base = Wt + (size_t)l * WT_LSTR;
    float v; int off_hi, off_lo;
    if (r < 196608) {                 // QKVt: n = r>>8, k = r&255
        int n = r >> 8, k = r & 255;
        int mat = n >> 8, hd = (n & 255) >> 5, dk = n & 31;
        const float* Wsel = (mat == 0) ? Wq : ((mat == 1) ? Wk : Wv);
        v = Wsel[(((size_t)l * HH + hd) * DDIM + k) * DKK + dk];
        off_hi = r; off_lo = r + 196608;
    } else if (r < 262144) {          // Wot
        int r2 = r - 196608;
        int n = r2 >> 8, k = r2 & 255;
        int hd = k >> 5, dk = k & 31;
        v = Wo[(((size_t)l * HH + hd) * DKK + dk) * DDIM + n];
        off_hi = 393216 + r2; off_lo = 458752 + r2;
    } else if (r < 393216) {          // FF1t
        int r3 = r - 262144;
        int n = r3 >> 8, k = r3 & 255;
        v = ffW1[((size_t)l * DDIM + k) * FFF + n];
        off_hi = 524288 + r3; off_lo = 655360 + r3;
    } else {                          // FF2t
        int r4 = r - 393216;
        int n = r4 >> 9, k = r4 & 511;
        v = ffW2[((size_t)l * FFF + k) * DDIM + n];
        off_hi = 786432 + r4; off_lo = 917504 + r4;
    }
    u16 hv = f2bf(v);
    base[off_hi] = hv;
    base[off_lo] = f2bf(v - bf2f(hv));
}

// ---------------------------------------------------------------------------
// Edge MLP is a scalar->R^8 piecewise-linear function: build a LUT once.
__global__ __launch_bounds__(256) void build_lut_kernel(
    const float* __restrict__ eW1, const float* __restrict__ eb1,
    const float* __restrict__ eW2, const float* __restrict__ eb2,
    const float* __restrict__ eW3, const float* __restrict__ eb3,
    float* __restrict__ lut)  // (LUTN+1) x 8
{
    int i = blockIdx.x * 256 + threadIdx.x;
    if (i > LUTN) return;
    float e = (float)i * (1.0f / LUTN);
    float t1[16], t2[16];
    #pragma unroll
    for (int a = 0; a < 16; ++a) t1[a] = fmaxf(e * eW1[a] + eb1[a], 0.0f);
    #pragma unroll
    for (int j = 0; j < 16; ++j) {
        float s = eb2[j];
        #pragma unroll
        for (int a = 0; a < 16; ++a) s += t1[a] * eW2[a * 16 + j];
        t2[j] = fmaxf(s, 0.0f);
    }
    #pragma unroll
    for (int hd = 0; hd < 8; ++hd) {
        float s = eb3[hd];
        #pragma unroll
        for (int j = 0; j < 16; ++j) s += t2[j] * eW3[j * 8 + hd];
        lut[(size_t)i * 8 + hd] = s;
    }
}

// bias[hd][b][i][j] (bf16) = lerp(LUT, edge[b,i,j])
__global__ __launch_bounds__(256) void edge_bias_kernel(
    const float* __restrict__ edge, const float* __restrict__ lut,
    u16* __restrict__ bout)
{
    size_t idx = (size_t)blockIdx.x * 256 + threadIdx.x;
    float e = edge[idx];
    float f = e * (float)LUTN;
    f = fminf(fmaxf(f, 0.0f), (float)LUTN - 0.0001f);
    int i0 = (int)f;
    float fr = f - (float)i0;
    const float4* r = (const float4*)(lut + (size_t)i0 * 8);
    float4 a0 = r[0], a1 = r[1], b0 = r[2], b1 = r[3];
    float o[8];
    o[0] = a0.x + fr * (b0.x - a0.x);
    o[1] = a0.y + fr * (b0.y - a0.y);
    o[2] = a0.z + fr * (b0.z - a0.z);
    o[3] = a0.w + fr * (b0.w - a0.w);
    o[4] = a1.x + fr * (b1.x - a1.x);
    o[5] = a1.y + fr * (b1.y - a1.y);
    o[6] = a1.z + fr * (b1.z - a1.z);
    o[7] = a1.w + fr * (b1.w - a1.w);
    #pragma unroll
    for (int hd = 0; hd < 8; ++hd)
        bout[(size_t)hd * (size_t)BB * NNN * NNN + idx] = f2bf(o[hd]);
}

// ---------------------------------------------------------------------------
// GEMM v2: inputs PRE-SPLIT bf16 (A [M][K] hi/lo, Bt [N][K] hi/lo transposed).
// C = Ah*Bh + Ah*Bl + Al*Bh (f32-equivalent). Tile 128x64, BK=64, 4 waves.
// launch_bounds (256,2): allow up to 256 VGPR; if allocator stays <=128 the
// HW still co-schedules 4 blocks/CU (LDS 36.9KB permits it).
__global__ __launch_bounds__(256, 2) void gemm2_kernel(
    const u16* __restrict__ Ah_g, const u16* __restrict__ Al_g, int K,
    const u16* __restrict__ Bth, const u16* __restrict__ Btl, int N,
    float* __restrict__ Cf,
    u16* __restrict__ Chi, u16* __restrict__ Clo,
    const float* __restrict__ bias, int relu,
    const float* __restrict__ res)
{
    __shared__ __align__(16) u16 Ah[128][72];   // 144B rows: 16B-aligned, 2-way max
    __shared__ __align__(16) u16 Al[128][72];
    int m0 = blockIdx.y * 128, n0 = blockIdx.x * 64;
    int tid = threadIdx.x, lid = tid & 63, wid = tid >> 6;
    int wm = wid >> 1, wn = wid & 1;
    int l15 = lid & 15, l4 = lid >> 4;

    f32x4 acc[4][2] = {};

    for (int k0 = 0; k0 < K; k0 += 64) {
        // stage A hi/lo: 128x64 bf16 each (pure copies, no conversion)
        #pragma unroll
        for (int j = 0; j < 4; ++j) {
            int c = tid + 256 * j;          // 1024 chunks of 8 elems
            int row = c >> 3, col8 = c & 7;
            bf16x8 vh = *(const bf16x8*)&Ah_g[(size_t)(m0 + row) * K + k0 + col8 * 8];
            bf16x8 vl = *(const bf16x8*)&Al_g[(size_t)(m0 + row) * K + k0 + col8 * 8];
            *(bf16x8*)&Ah[row][col8 * 8] = vh;
            *(bf16x8*)&Al[row][col8 * 8] = vl;
        }
        __syncthreads();
        #pragma unroll
        for (int ks = 0; ks < 2; ++ks) {
            int ko = ks * 32;
            bf16x8 afh[4], afl[4], bfh[2], bfl[2];
            #pragma unroll
            for (int mi = 0; mi < 4; ++mi) {
                afh[mi] = *(const bf16x8*)&Ah[wm * 64 + mi * 16 + l15][ko + l4 * 8];
                afl[mi] = *(const bf16x8*)&Al[wm * 64 + mi * 16 + l15][ko + l4 * 8];
            }
            #pragma unroll
            for (int ni = 0; ni < 2; ++ni) {
                size_t brow = (size_t)(n0 + wn * 32 + ni * 16 + l15) * K + k0 + ko + l4 * 8;
                bfh[ni] = *(const bf16x8*)&Bth[brow];
                bfl[ni] = *(const bf16x8*)&Btl[brow];
            }
            #pragma unroll
            for (int mi = 0; mi < 4; ++mi)
                #pragma unroll
                for (int ni = 0; ni < 2; ++ni) {
                    acc[mi][ni] = __builtin_amdgcn_mfma_f32_16x16x32_bf16(
                        afh[mi], bfh[ni], acc[mi][ni], 0, 0, 0);
                    acc[mi][ni] = __builtin_amdgcn_mfma_f32_16x16x32_bf16(
                        afh[mi], bfl[ni], acc[mi][ni], 0, 0, 0);
                    acc[mi][ni] = __builtin_amdgcn_mfma_f32_16x16x32_bf16(
                        afl[mi], bfh[ni], acc[mi][ni], 0, 0, 0);
                }
        }
        __syncthreads();
    }
    // epilogue
    #pragma unroll
    for (int mi = 0; mi < 4; ++mi) {
        #pragma unroll
        for (int ni = 0; ni < 2; ++ni) {
            #pragma unroll
            for (int r = 0; r < 4; ++r) {
                int row = m0 + wm * 64 + mi * 16 + l4 * 4 + r;
                int col = n0 + wn * 32 + ni * 16 + l15;
                float v = acc[mi][ni][r];
                if (bias) v += bias[col];
                if (relu) v = fmaxf(v, 0.0f);
                if (res)  v += res[(size_t)row * N + col];
                size_t o = (size_t)row * N + col;
                if (Cf) Cf[o] = v;
                if (Chi) {
                    u16 hv = f2bf(v);
                    Chi[o] = hv;
                    Clo[o] = f2bf(v - bf2f(hv));
                }
            }
        }
    }
}

// ---------------------------------------------------------------------------
// MFMA fused attention v3.1: same as v3 but launch_bounds (512,1) —
// LDS (115KB) already bounds to 1 block/CU, so VGPR may go to 256.
// acc[32] (128 VGPR) + frags must NOT spill (round-9 spill: VGPR capped 128,
// WRITE_SIZE 97MB of scratch traffic).
__global__ __launch_bounds__(512, 1) void attn_mfma_kernel(
    const u16* __restrict__ qkv_hi, const u16* __restrict__ qkv_lo,
    const u16* __restrict__ bias,
    u16* __restrict__ attb_hi, u16* __restrict__ attb_lo)
{
    __shared__ __align__(16) u16 Ksh[512][40];   // 80B rows: 16B-aligned, 2-way max
    __shared__ __align__(16) u16 UB[512 * 40];   // union: Ksl[512][40] | Pw[8][16][72]
    __shared__ __align__(16) u16 Vt[32][520];
    int wg = blockIdx.x;
    int logical = (wg & 7) * 64 + (wg >> 3);   // bijective (512 % 8 == 0)
    int qt = logical & 3, hd = (logical >> 2) & 7, b = logical >> 5;
    int tid = threadIdx.x, lid = tid & 63, w = tid >> 6;
    int l15 = lid & 15, l4 = lid >> 4;

    const u16* baseh = qkv_hi + (size_t)b * 512 * 768;
    const u16* basel = qkv_lo + (size_t)b * 512 * 768;
    u16 (*Ksl)[40] = (u16(*)[40])UB;

    // stage K hi/lo + V hi (pure bf16 copies, coalesced ushort4)
    for (int q4 = tid; q4 < 512 * 8; q4 += 512) {
        int n = q4 >> 3, c4 = q4 & 7;
        ushort4 kh = *(const ushort4*)&baseh[(size_t)n * 768 + 256 + hd * 32 + c4 * 4];
        ushort4 kl = *(const ushort4*)&basel[(size_t)n * 768 + 256 + hd * 32 + c4 * 4];
        ushort4 vh = *(const ushort4*)&baseh[(size_t)n * 768 + 512 + hd * 32 + c4 * 4];
        *(ushort4*)&Ksh[n][c4 * 4] = kh;
        *(ushort4*)&Ksl[n][c4 * 4] = kl;
        Vt[c4 * 4 + 0][n] = vh.x;
        Vt[c4 * 4 + 1][n] = vh.y;
        Vt[c4 * 4 + 2][n] = vh.z;
        Vt[c4 * 4 + 3][n] = vh.w;
    }
    __syncthreads();

    int qw0 = qt * 128 + w * 16;
    // Q A-frags hi/lo: direct 16B global loads (no conversion)
    bf16x8 afh = *(const bf16x8*)&baseh[(size_t)(qw0 + l15) * 768 + hd * 32 + l4 * 8];
    bf16x8 afl = *(const bf16x8*)&basel[(size_t)(qw0 + l15) * 768 + hd * 32 + l4 * 8];

    // scores: S = Qh·Kh + Ql·Kh + Qh·Kl over 32 col-tiles
    f32x4 acc[32];
    #pragma unroll
    for (int ct = 0; ct < 32; ++ct) {
        bf16x8 bh = *(const bf16x8*)&Ksh[ct * 16 + l15][l4 * 8];
        bf16x8 bl = *(const bf16x8*)&Ksl[ct * 16 + l15][l4 * 8];
        f32x4 z = {0.0f, 0.0f, 0.0f, 0.0f};
        z = __builtin_amdgcn_mfma_f32_16x16x32_bf16(afh, bh, z, 0, 0, 0);
        z = __builtin_amdgcn_mfma_f32_16x16x32_bf16(afl, bh, z, 0, 0, 0);
        acc[ct] = __builtin_amdgcn_mfma_f32_16x16x32_bf16(afh, bl, z, 0, 0, 0);
    }
    __syncthreads();   // all waves done with Ksl before Pw overwrites UB

    const float scale = 0.17677669529663687f;  // 1/sqrt(32)
    if (bias) {
        size_t brow = (((size_t)hd * BB + b) * NNN + qw0 + l4 * 4) * NNN + l15;
        #pragma unroll
        for (int ct = 0; ct < 32; ++ct)
            #pragma unroll
            for (int r = 0; r < 4; ++r)
                acc[ct][r] = acc[ct][r] * scale +
                             bf2f(bias[brow + (size_t)r * NNN + ct * 16]);
    } else {
        #pragma unroll
        for (int ct = 0; ct < 32; ++ct)
            #pragma unroll
            for (int r = 0; r < 4; ++r)
                acc[ct][r] *= scale;
    }

    // in-fragment softmax per row
    float linv[4];
    #pragma unroll
    for (int r = 0; r < 4; ++r) {
        float m = acc[0][r];
        #pragma unroll
        for (int ct = 1; ct < 32; ++ct) m = fmaxf(m, acc[ct][r]);
        #pragma unroll
        for (int msk = 1; msk < 16; msk <<= 1) m = fmaxf(m, __shfl_xor(m, msk));
        float lsum = 0.0f;
        #pragma unroll
        for (int ct = 0; ct < 32; ++ct) {
            float p = __expf(acc[ct][r] - m);
            acc[ct][r] = p;
            lsum += p;
        }
        #pragma unroll
        for (int msk = 1; msk < 16; msk <<= 1) lsum += __shfl_xor(lsum, msk);
        linv[r] = 1.0f / lsum;
    }

    // PV in 8 kv-chunks of 64 via per-wave P buffer in UB (intra-wave ordering)
    u16 (*Pw)[72] = (u16(*)[72])(UB + w * 16 * 72);
    f32x4 oacc[2] = {};
    for (int cc = 0; cc < 8; ++cc) {
        #pragma unroll
        for (int ct4 = 0; ct4 < 4; ++ct4) {
            int ct = cc * 4 + ct4;
            #pragma unroll
            for (int r = 0; r < 4; ++r)
                Pw[l4 * 4 + r][ct4 * 16 + l15] = f2bf(acc[ct][r]);
        }
        #pragma unroll
        for (int ks = 0; ks < 2; ++ks) {
            bf16x8 pa = *(const bf16x8*)&Pw[l15][ks * 32 + l4 * 8];
            #pragma unroll
            for (int ct2 = 0; ct2 < 2; ++ct2) {
                bf16x8 vb = *(const bf16x8*)&Vt[ct2 * 16 + l15][cc * 64 + ks * 32 + l4 * 8];
                oacc[ct2] = __builtin_amdgcn_mfma_f32_16x16x32_bf16(pa, vb, oacc[ct2], 0, 0, 0);
            }
        }
    }
    // epilogue: split-write attb
    #pragma unroll
    for (int ct2 = 0; ct2 < 2; ++ct2)
        #pragma unroll
        for (int r = 0; r < 4; ++r) {
            float o = oacc[ct2][r] * linv[r];
            size_t oi = ((size_t)b * NNN + qw0 + l4 * 4 + r) * DDIM + hd * 32 + ct2 * 16 + l15;
            u16 hv = f2bf(o);
            attb_hi[oi] = hv;
            attb_lo[oi] = f2bf(o - bf2f(hv));
        }
}

// ---------------------------------------------------------------------------
__global__ void zero_stats_kernel(float* stats)
{
    stats[threadIdx.x] = 0.0f;
    stats[256 + threadIdx.x] = 0.0f;
}

__global__ __launch_bounds__(256) void bn_stats_kernel(
    const float* __restrict__ X, float* __restrict__ stats)
{
    int c = threadIdx.x;
    size_t r0 = (size_t)blockIdx.x * 32;
    float s = 0.0f, ss = 0.0f;
    for (int r = 0; r < 32; ++r) {
        float v = X[(r0 + r) * DDIM + c];
        s += v; ss += v * v;
    }
    atomicAdd(&stats[c], s);
    atomicAdd(&stats[256 + c], ss);
}

__global__ __launch_bounds__(256) void bn_apply_kernel(
    const float* __restrict__ X, float* __restrict__ Y,
    u16* __restrict__ Yhi, u16* __restrict__ Ylo,
    const float* __restrict__ stats,
    const float* __restrict__ g, const float* __restrict__ bb)
{
    int c = threadIdx.x;
    float mean = stats[c] * (1.0f / MROWS);
    float var  = stats[256 + c] * (1.0f / MROWS) - mean * mean;
    float inv  = rsqrtf(var + 1e-5f);
    float gg = g[c] * inv;
    float off = bb[c] - mean * gg;
    size_t r0 = (size_t)blockIdx.x * 8;
    #pragma unroll
    for (int r = 0; r < 8; ++r) {
        size_t o = (r0 + r) * DDIM + c;
        float y = X[o] * gg + off;
        Y[o] = y;
        if (Yhi) {
            u16 hv = f2bf(y);
            Yhi[o] = hv;
            Ylo[o] = f2bf(y - bf2f(hv));
        }
    }
}

__global__ __launch_bounds__(256) void graph_embed_kernel(
    const float* __restrict__ outh, float* __restrict__ outg)
{
    int c = threadIdx.x, b = blockIdx.x;
    float s = 0.0f;
    for (int n = 0; n < NNN; ++n)
        s += outh[((size_t)b * NNN + n) * DDIM + c];
    outg[b * DDIM + c] = s * (1.0f / NNN);
}

// ---------------------------------------------------------------------------
extern "C" void kernel_launch(void* const* d_in, const int* in_sizes, int n_in,
                              void* d_out, int out_size, void* d_ws, size_t ws_size,
                              hipStream_t stream)
{
    const float* x     = (const float*)d_in[0];
    const float* edge  = (const float*)d_in[1];
    const float* initW = (const float*)d_in[2];
    const float* initb = (const float*)d_in[3];
    const float* Wq    = (const float*)d_in[4];
    const float* Wk    = (const float*)d_in[5];
    const float* Wv    = (const float*)d_in[6];
    const float* Wo    = (const float*)d_in[7];
    const float* eW1   = (const float*)d_in[8];
    const float* eb1   = (const float*)d_in[9];
    const float* eW2   = (const float*)d_in[10];
    const float* eb2   = (const float*)d_in[11];
    const float* eW3   = (const float*)d_in[12];
    const float* eb3   = (const float*)d_in[13];
    const float* bn1g  = (const float*)d_in[14];
    const float* bn1b  = (const float*)d_in[15];
    const float* ffW1  = (const float*)d_in[16];
    const float* ffb1  = (const float*)d_in[17];
    const float* ffW2  = (const float*)d_in[18];
    const float* ffb2  = (const float*)d_in[19];
    const float* bn2g  = (const float*)d_in[20];
    const float* bn2b  = (const float*)d_in[21];

    char* ws = (char*)d_ws;
    float* h      = (float*)(ws);                            //  8 MB @0
    float* h2     = (float*)(ws + ((size_t)8  << 20));       //  8 MB @8
    u16*   h_hi   = (u16*)  (ws + ((size_t)16 << 20));       //  4 MB @16 (alias attb_hi)
    u16*   h_lo   = (u16*)  (ws + ((size_t)20 << 20));       //  4 MB @20 (alias attb_lo)
    u16*   qkv_hi = (u16*)  (ws + ((size_t)24 << 20));       // 12 MB @24 (alias ff_hi 8MB)
    u16*   qkv_lo = (u16*)  (ws + ((size_t)36 << 20));       // 12 MB @36 (alias ff_lo 8MB)
    float* stats  = (float*)(ws + ((size_t)48 << 20));       //  2 KB @48
    float* lut    = (float*)(ws + ((size_t)48 << 20) + 4096);// ~131 KB
    u16*   Wt     = (u16*)  (ws + ((size_t)49 << 20));       //  6 MB @49
    u16*   bias   = (u16*)  (ws + ((size_t)56 << 20));       // 64 MB @56 (end 120 MB)
    u16*   attb_hi = h_hi;
    u16*   attb_lo = h_lo;
    u16*   ff_hi   = qkv_hi;
    u16*   ff_lo   = qkv_lo;
    float* outh  = (float*)d_out;
    float* outg  = outh + (size_t)MROWS * DDIM;

    wsplit_kernel<<<6144, 256, 0, stream>>>(Wq, Wk, Wv, Wo, ffW1, ffW2, Wt);
    init_embed_kernel<<<MROWS, 256, 0, stream>>>(x, initW, initb, h, h_hi, h_lo);
    build_lut_kernel<<<17, 256, 0, stream>>>(eW1, eb1, eW2, eb2, eW3, eb3, lut);
    edge_bias_kernel<<<(BB * NNN * NNN) / 256, 256, 0, stream>>>(edge, lut, bias);

    for (int l = 0; l < 3; ++l) {
        u16* WL = Wt + (size_t)l * WT_LSTR;
        // QKV projection -> split qkv
        gemm2_kernel<<<dim3(12, 64), 256, 0, stream>>>(
            h_hi, h_lo, 256, WL, WL + 196608, 768,
            nullptr, qkv_hi, qkv_lo, nullptr, 0, nullptr);
        // fused MFMA attention -> split attb (overwrites h_hi/h_lo region)
        attn_mfma_kernel<<<512, 512, 0, stream>>>(
            qkv_hi, qkv_lo, (l == 0) ? bias : (const u16*)nullptr, attb_hi, attb_lo);
        // Wo projection + residual: h2 = h + attb @ Wo
        gemm2_kernel<<<dim3(4, 64), 256, 0, stream>>>(
            attb_hi, attb_lo, 256, WL + 393216, WL + 458752, 256,
            h2, nullptr, nullptr, nullptr, 0, h);
        zero_stats_kernel<<<1, 256, 0, stream>>>(stats);
        bn_stats_kernel<<<256, 256, 0, stream>>>(h2, stats);
        bn_apply_kernel<<<1024, 256, 0, stream>>>(
            h2, h, h_hi, h_lo, stats, bn1g + l * 256, bn1b + l * 256);
        // FF1: relu(h @ W1 + b1) -> split ff (overwrites qkv region)
        gemm2_kernel<<<dim3(8, 64), 256, 0, stream>>>(
            h_hi, h_lo, 256, WL + 524288, WL + 655360, 512,
            nullptr, ff_hi, ff_lo, ffb1 + l * 512, 1, nullptr);
        // FF2 + bias + residual: h2 = h + ff @ W2 + b2
        gemm2_kernel<<<dim3(4, 64), 256, 0, stream>>>(
            ff_hi, ff_lo, 512, WL + 786432, WL + 917504, 256,
            h2, nullptr, nullptr, ffb2 + l * 256, 0, h);
        zero_stats_kernel<<<1, 256, 0, stream>>>(stats);
        bn_stats_kernel<<<256, 256, 0, stream>>>(h2, stats);
        if (l == 2)
            bn_apply_kernel<<<1024, 256, 0, stream>>>(
                h2, outh, nullptr, nullptr, stats, bn2g + l * 256, bn2b + l * 256);
        else
            bn_apply_kernel<<<1024, 256, 0, stream>>>(
                h2, h, h_hi, h_lo, stats, bn2g + l * 256, bn2b + l * 256);
    }
    graph_embed_kernel<<<BB, 256, 0, stream>>>(outh, outg);
}

// Round 11
// 742.317 us; speedup vs baseline: 1.1136x; 1.0049x over previous
//
#include <hip/hip_runtime.h>

// Shapes (fixed per reference)
#define BB    16
#define NNN   512
#define DDIM  256
#define HH    8
#define DKK   32
#define FFF   512
#define MROWS 8192   // B*N
#define LUTN  4096

using u16    = unsigned short;
using bf16x8 = __attribute__((ext_vector_type(8))) short;
using f32x4  = __attribute__((ext_vector_type(4))) float;

__device__ __forceinline__ float bf2f(u16 u) { return __uint_as_float(((unsigned)u) << 16); }
__device__ __forceinline__ u16 f2bf(float f) {
    unsigned u = __float_as_uint(f);
    return (u16)((u + 0x7fffu + ((u >> 16) & 1u)) >> 16);  // RNE
}

// ---------------------------------------------------------------------------
// h = x @ init_W + init_b ; also emit h_hi/h_lo bf16 split
__global__ __launch_bounds__(256) void init_embed_kernel(
    const float* __restrict__ x, const float* __restrict__ W,
    const float* __restrict__ b, float* __restrict__ h,
    u16* __restrict__ hhi, u16* __restrict__ hlo)
{
    size_t row = blockIdx.x;
    int c = threadIdx.x;
    float x0 = x[row * 2 + 0], x1 = x[row * 2 + 1];
    float v = x0 * W[c] + x1 * W[DDIM + c] + b[c];
    size_t o = row * DDIM + c;
    h[o] = v;
    u16 hv = f2bf(v);
    hhi[o] = hv;
    hlo[o] = f2bf(v - bf2f(hv));
}

// ---------------------------------------------------------------------------
// One-shot weight transpose + hi/lo split.  Per layer (u16-elem offsets within
// a 1048576-elem layer block):
//   QKVt [768][256]  hi@0       lo@196608
//   Wot  [256][256]  hi@393216  lo@458752
//   FF1t [512][256]  hi@524288  lo@655360
//   FF2t [256][512]  hi@786432  lo@917504
#define WT_LSTR 1048576
__global__ __launch_bounds__(256) void wsplit_kernel(
    const float* __restrict__ Wq, const float* __restrict__ Wk,
    const float* __restrict__ Wv, const float* __restrict__ Wo,
    const float* __restrict__ ffW1, const float* __restrict__ ffW2,
    u16* __restrict__ Wt)
{
    int fid = blockIdx.x * 256 + threadIdx.x;   // 3 * 524288 total
    int l = fid >> 19, r = fid & 524287;
    u16* base = Wt + (size_t)l * WT_LSTR;
    float v; int off_hi, off_lo;
    if (r < 196608) {                 // QKVt: n = r>>8, k = r&255
        int n = r >> 8, k = r & 255;
        int mat = n >> 8, hd = (n & 255) >> 5, dk = n & 31;
        const float* Wsel = (mat == 0) ? Wq : ((mat == 1) ? Wk : Wv);
        v = Wsel[(((size_t)l * HH + hd) * DDIM + k) * DKK + dk];
        off_hi = r; off_lo = r + 196608;
    } else if (r < 262144) {          // Wot
        int r2 = r - 196608;
        int n = r2 >> 8, k = r2 & 255;
        int hd = k >> 5, dk = k & 31;
        v = Wo[(((size_t)l * HH + hd) * DKK + dk) * DDIM + n];
        off_hi = 393216 + r2; off_lo = 458752 + r2;
    } else if (r < 393216) {          // FF1t
        int r3 = r - 262144;
        int n = r3 >> 8, k = r3 & 255;
        v = ffW1[((size_t)l * DDIM + k) * FFF + n];
        off_hi = 524288 + r3; off_lo = 655360 + r3;
    } else {                          // FF2t
        int r4 = r - 393216;
        int n = r4 >> 9, k = r4 & 511;
        v = ffW2[((size_t)l * FFF + k) * DDIM + n];
        off_hi = 786432 + r4; off_lo = 917504 + r4;
    }
    u16 hv = f2bf(v);
    base[off_hi] = hv;
    base[off_lo] = f2bf(v - bf2f(hv));
}

// ---------------------------------------------------------------------------
// Edge MLP is a scalar->R^8 piecewise-linear function: build a LUT once.
__global__ __launch_bounds__(256) void build_lut_kernel(
    const float* __restrict__ eW1, const float* __restrict__ eb1,
    const float* __restrict__ eW2, const float* __restrict__ eb2,
    const float* __restrict__ eW3, const float* __restrict__ eb3,
    float* __restrict__ lut)  // (LUTN+1) x 8
{
    int i = blockIdx.x * 256 + threadIdx.x;
    if (i > LUTN) return;
    float e = (float)i * (1.0f / LUTN);
    float t1[16], t2[16];
    #pragma unroll
    for (int a = 0; a < 16; ++a) t1[a] = fmaxf(e * eW1[a] + eb1[a], 0.0f);
    #pragma unroll
    for (int j = 0; j < 16; ++j) {
        float s = eb2[j];
        #pragma unroll
        for (int a = 0; a < 16; ++a) s += t1[a] * eW2[a * 16 + j];
        t2[j] = fmaxf(s, 0.0f);
    }
    #pragma unroll
    for (int hd = 0; hd < 8; ++hd) {
        float s = eb3[hd];
        #pragma unroll
        for (int j = 0; j < 16; ++j) s += t2[j] * eW3[j * 8 + hd];
        lut[(size_t)i * 8 + hd] = s;
    }
}

// bias[hd][b][i][j] (bf16) = lerp(LUT, edge[b,i,j])
__global__ __launch_bounds__(256) void edge_bias_kernel(
    const float* __restrict__ edge, const float* __restrict__ lut,
    u16* __restrict__ bout)
{
    size_t idx = (size_t)blockIdx.x * 256 + threadIdx.x;
    float e = edge[idx];
    float f = e * (float)LUTN;
    f = fminf(fmaxf(f, 0.0f), (float)LUTN - 0.0001f);
    int i0 = (int)f;
    float fr = f - (float)i0;
    const float4* r = (const float4*)(lut + (size_t)i0 * 8);
    float4 a0 = r[0], a1 = r[1], b0 = r[2], b1 = r[3];
    float o[8];
    o[0] = a0.x + fr * (b0.x - a0.x);
    o[1] = a0.y + fr * (b0.y - a0.y);
    o[2] = a0.z + fr * (b0.z - a0.z);
    o[3] = a0.w + fr * (b0.w - a0.w);
    o[4] = a1.x + fr * (b1.x - a1.x);
    o[5] = a1.y + fr * (b1.y - a1.y);
    o[6] = a1.z + fr * (b1.z - a1.z);
    o[7] = a1.w + fr * (b1.w - a1.w);
    #pragma unroll
    for (int hd = 0; hd < 8; ++hd)
        bout[(size_t)hd * (size_t)BB * NNN * NNN + idx] = f2bf(o[hd]);
}

// ---------------------------------------------------------------------------
// GEMM v2: inputs PRE-SPLIT bf16 (A [M][K] hi/lo, Bt [N][K] hi/lo transposed).
// C = Ah*Bh + Ah*Bl + Al*Bh (f32-equivalent). Tile 128x64, BK=64, 4 waves.
__global__ __launch_bounds__(256, 2) void gemm2_kernel(
    const u16* __restrict__ Ah_g, const u16* __restrict__ Al_g, int K,
    const u16* __restrict__ Bth, const u16* __restrict__ Btl, int N,
    float* __restrict__ Cf,
    u16* __restrict__ Chi, u16* __restrict__ Clo,
    const float* __restrict__ bias, int relu,
    const float* __restrict__ res)
{
    __shared__ __align__(16) u16 Ah[128][72];   // 144B rows: 16B-aligned, 2-way max
    __shared__ __align__(16) u16 Al[128][72];
    int m0 = blockIdx.y * 128, n0 = blockIdx.x * 64;
    int tid = threadIdx.x, lid = tid & 63, wid = tid >> 6;
    int wm = wid >> 1, wn = wid & 1;
    int l15 = lid & 15, l4 = lid >> 4;

    f32x4 acc[4][2] = {};

    for (int k0 = 0; k0 < K; k0 += 64) {
        // stage A hi/lo: 128x64 bf16 each (pure copies, no conversion)
        #pragma unroll
        for (int j = 0; j < 4; ++j) {
            int c = tid + 256 * j;          // 1024 chunks of 8 elems
            int row = c >> 3, col8 = c & 7;
            bf16x8 vh = *(const bf16x8*)&Ah_g[(size_t)(m0 + row) * K + k0 + col8 * 8];
            bf16x8 vl = *(const bf16x8*)&Al_g[(size_t)(m0 + row) * K + k0 + col8 * 8];
            *(bf16x8*)&Ah[row][col8 * 8] = vh;
            *(bf16x8*)&Al[row][col8 * 8] = vl;
        }
        __syncthreads();
        #pragma unroll
        for (int ks = 0; ks < 2; ++ks) {
            int ko = ks * 32;
            bf16x8 afh[4], afl[4], bfh[2], bfl[2];
            #pragma unroll
            for (int mi = 0; mi < 4; ++mi) {
                afh[mi] = *(const bf16x8*)&Ah[wm * 64 + mi * 16 + l15][ko + l4 * 8];
                afl[mi] = *(const bf16x8*)&Al[wm * 64 + mi * 16 + l15][ko + l4 * 8];
            }
            #pragma unroll
            for (int ni = 0; ni < 2; ++ni) {
                size_t brow = (size_t)(n0 + wn * 32 + ni * 16 + l15) * K + k0 + ko + l4 * 8;
                bfh[ni] = *(const bf16x8*)&Bth[brow];
                bfl[ni] = *(const bf16x8*)&Btl[brow];
            }
            #pragma unroll
            for (int mi = 0; mi < 4; ++mi)
                #pragma unroll
                for (int ni = 0; ni < 2; ++ni) {
                    acc[mi][ni] = __builtin_amdgcn_mfma_f32_16x16x32_bf16(
                        afh[mi], bfh[ni], acc[mi][ni], 0, 0, 0);
                    acc[mi][ni] = __builtin_amdgcn_mfma_f32_16x16x32_bf16(
                        afh[mi], bfl[ni], acc[mi][ni], 0, 0, 0);
                    acc[mi][ni] = __builtin_amdgcn_mfma_f32_16x16x32_bf16(
                        afl[mi], bfh[ni], acc[mi][ni], 0, 0, 0);
                }
        }
        __syncthreads();
    }
    // epilogue
    #pragma unroll
    for (int mi = 0; mi < 4; ++mi) {
        #pragma unroll
        for (int ni = 0; ni < 2; ++ni) {
            #pragma unroll
            for (int r = 0; r < 4; ++r) {
                int row = m0 + wm * 64 + mi * 16 + l4 * 4 + r;
                int col = n0 + wn * 32 + ni * 16 + l15;
                float v = acc[mi][ni][r];
                if (bias) v += bias[col];
                if (relu) v = fmaxf(v, 0.0f);
                if (res)  v += res[(size_t)row * N + col];
                size_t o = (size_t)row * N + col;
                if (Cf) Cf[o] = v;
                if (Chi) {
                    u16 hv = f2bf(v);
                    Chi[o] = hv;
                    Clo[o] = f2bf(v - bf2f(hv));
                }
            }
        }
    }
}

// ---------------------------------------------------------------------------
// MFMA fused attention v3.2: v3.1 + FULLY UNROLLED PV chunk loop.
// Round-10 lesson (rule #20): the runtime `cc` loop made acc[ct] runtime-
// indexed -> all 128 acc VGPRs went to scratch (95MB HBM writes/dispatch).
// #pragma unroll makes every acc index compile-time -> registers.
__global__ __launch_bounds__(512, 1) void attn_mfma_kernel(
    const u16* __restrict__ qkv_hi, const u16* __restrict__ qkv_lo,
    const u16* __restrict__ bias,
    u16* __restrict__ attb_hi, u16* __restrict__ attb_lo)
{
    __shared__ __align__(16) u16 Ksh[512][40];   // 80B rows: 16B-aligned, 2-way max
    __shared__ __align__(16) u16 UB[512 * 40];   // union: Ksl[512][40] | Pw[8][16][72]
    __shared__ __align__(16) u16 Vt[32][520];
    int wg = blockIdx.x;
    int logical = (wg & 7) * 64 + (wg >> 3);   // bijective (512 % 8 == 0)
    int qt = logical & 3, hd = (logical >> 2) & 7, b = logical >> 5;
    int tid = threadIdx.x, lid = tid & 63, w = tid >> 6;
    int l15 = lid & 15, l4 = lid >> 4;

    const u16* baseh = qkv_hi + (size_t)b * 512 * 768;
    const u16* basel = qkv_lo + (size_t)b * 512 * 768;
    u16 (*Ksl)[40] = (u16(*)[40])UB;

    // stage K hi/lo + V hi (pure bf16 copies, coalesced ushort4)
    for (int q4 = tid; q4 < 512 * 8; q4 += 512) {
        int n = q4 >> 3, c4 = q4 & 7;
        ushort4 kh = *(const ushort4*)&baseh[(size_t)n * 768 + 256 + hd * 32 + c4 * 4];
        ushort4 kl = *(const ushort4*)&basel[(size_t)n * 768 + 256 + hd * 32 + c4 * 4];
        ushort4 vh = *(const ushort4*)&baseh[(size_t)n * 768 + 512 + hd * 32 + c4 * 4];
        *(ushort4*)&Ksh[n][c4 * 4] = kh;
        *(ushort4*)&Ksl[n][c4 * 4] = kl;
        Vt[c4 * 4 + 0][n] = vh.x;
        Vt[c4 * 4 + 1][n] = vh.y;
        Vt[c4 * 4 + 2][n] = vh.z;
        Vt[c4 * 4 + 3][n] = vh.w;
    }
    __syncthreads();

    int qw0 = qt * 128 + w * 16;
    // Q A-frags hi/lo: direct 16B global loads (no conversion)
    bf16x8 afh = *(const bf16x8*)&baseh[(size_t)(qw0 + l15) * 768 + hd * 32 + l4 * 8];
    bf16x8 afl = *(const bf16x8*)&basel[(size_t)(qw0 + l15) * 768 + hd * 32 + l4 * 8];

    // scores: S = Qh·Kh + Ql·Kh + Qh·Kl over 32 col-tiles
    f32x4 acc[32];
    #pragma unroll
    for (int ct = 0; ct < 32; ++ct) {
        bf16x8 bh = *(const bf16x8*)&Ksh[ct * 16 + l15][l4 * 8];
        bf16x8 bl = *(const bf16x8*)&Ksl[ct * 16 + l15][l4 * 8];
        f32x4 z = {0.0f, 0.0f, 0.0f, 0.0f};
        z = __builtin_amdgcn_mfma_f32_16x16x32_bf16(afh, bh, z, 0, 0, 0);
        z = __builtin_amdgcn_mfma_f32_16x16x32_bf16(afl, bh, z, 0, 0, 0);
        acc[ct] = __builtin_amdgcn_mfma_f32_16x16x32_bf16(afh, bl, z, 0, 0, 0);
    }
    __syncthreads();   // all waves done with Ksl before Pw overwrites UB

    const float scale = 0.17677669529663687f;  // 1/sqrt(32)
    if (bias) {
        size_t brow = (((size_t)hd * BB + b) * NNN + qw0 + l4 * 4) * NNN + l15;
        #pragma unroll
        for (int ct = 0; ct < 32; ++ct)
            #pragma unroll
            for (int r = 0; r < 4; ++r)
                acc[ct][r] = acc[ct][r] * scale +
                             bf2f(bias[brow + (size_t)r * NNN + ct * 16]);
    } else {
        #pragma unroll
        for (int ct = 0; ct < 32; ++ct)
            #pragma unroll
            for (int r = 0; r < 4; ++r)
                acc[ct][r] *= scale;
    }

    // in-fragment softmax per row
    float linv[4];
    #pragma unroll
    for (int r = 0; r < 4; ++r) {
        float m = acc[0][r];
        #pragma unroll
        for (int ct = 1; ct < 32; ++ct) m = fmaxf(m, acc[ct][r]);
        #pragma unroll
        for (int msk = 1; msk < 16; msk <<= 1) m = fmaxf(m, __shfl_xor(m, msk));
        float lsum = 0.0f;
        #pragma unroll
        for (int ct = 0; ct < 32; ++ct) {
            float p = __expf(acc[ct][r] - m);
            acc[ct][r] = p;
            lsum += p;
        }
        #pragma unroll
        for (int msk = 1; msk < 16; msk <<= 1) lsum += __shfl_xor(lsum, msk);
        linv[r] = 1.0f / lsum;
    }

    // PV in 8 kv-chunks of 64 via per-wave P buffer in UB (intra-wave ordering)
    u16 (*Pw)[72] = (u16(*)[72])(UB + w * 16 * 72);
    f32x4 oacc[2] = {};
    #pragma unroll
    for (int cc = 0; cc < 8; ++cc) {
        #pragma unroll
        for (int ct4 = 0; ct4 < 4; ++ct4) {
            int ct = cc * 4 + ct4;
            #pragma unroll
            for (int r = 0; r < 4; ++r)
                Pw[l4 * 4 + r][ct4 * 16 + l15] = f2bf(acc[ct][r]);
        }
        #pragma unroll
        for (int ks = 0; ks < 2; ++ks) {
            bf16x8 pa = *(const bf16x8*)&Pw[l15][ks * 32 + l4 * 8];
            #pragma unroll
            for (int ct2 = 0; ct2 < 2; ++ct2) {
                bf16x8 vb = *(const bf16x8*)&Vt[ct2 * 16 + l15][cc * 64 + ks * 32 + l4 * 8];
                oacc[ct2] = __builtin_amdgcn_mfma_f32_16x16x32_bf16(pa, vb, oacc[ct2], 0, 0, 0);
            }
        }
    }
    // epilogue: split-write attb
    #pragma unroll
    for (int ct2 = 0; ct2 < 2; ++ct2)
        #pragma unroll
        for (int r = 0; r < 4; ++r) {
            float o = oacc[ct2][r] * linv[r];
            size_t oi = ((size_t)b * NNN + qw0 + l4 * 4 + r) * DDIM + hd * 32 + ct2 * 16 + l15;
            u16 hv = f2bf(o);
            attb_hi[oi] = hv;
            attb_lo[oi] = f2bf(o - bf2f(hv));
        }
}

// ---------------------------------------------------------------------------
__global__ void zero_stats_kernel(float* stats)
{
    stats[threadIdx.x] = 0.0f;
    stats[256 + threadIdx.x] = 0.0f;
}

__global__ __launch_bounds__(256) void bn_stats_kernel(
    const float* __restrict__ X, float* __restrict__ stats)
{
    int c = threadIdx.x;
    size_t r0 = (size_t)blockIdx.x * 32;
    float s = 0.0f, ss = 0.0f;
    for (int r = 0; r < 32; ++r) {
        float v = X[(r0 + r) * DDIM + c];
        s += v; ss += v * v;
    }
    atomicAdd(&stats[c], s);
    atomicAdd(&stats[256 + c], ss);
}

__global__ __launch_bounds__(256) void bn_apply_kernel(
    const float* __restrict__ X, float* __restrict__ Y,
    u16* __restrict__ Yhi, u16* __restrict__ Ylo,
    const float* __restrict__ stats,
    const float* __restrict__ g, const float* __restrict__ bb)
{
    int c = threadIdx.x;
    float mean = stats[c] * (1.0f / MROWS);
    float var  = stats[256 + c] * (1.0f / MROWS) - mean * mean;
    float inv  = rsqrtf(var + 1e-5f);
    float gg = g[c] * inv;
    float off = bb[c] - mean * gg;
    size_t r0 = (size_t)blockIdx.x * 8;
    #pragma unroll
    for (int r = 0; r < 8; ++r) {
        size_t o = (r0 + r) * DDIM + c;
        float y = X[o] * gg + off;
        Y[o] = y;
        if (Yhi) {
            u16 hv = f2bf(y);
            Yhi[o] = hv;
            Ylo[o] = f2bf(y - bf2f(hv));
        }
    }
}

__global__ __launch_bounds__(256) void graph_embed_kernel(
    const float* __restrict__ outh, float* __restrict__ outg)
{
    int c = threadIdx.x, b = blockIdx.x;
    float s = 0.0f;
    for (int n = 0; n < NNN; ++n)
        s += outh[((size_t)b * NNN + n) * DDIM + c];
    outg[b * DDIM + c] = s * (1.0f / NNN);
}

// ---------------------------------------------------------------------------
extern "C" void kernel_launch(void* const* d_in, const int* in_sizes, int n_in,
                              void* d_out, int out_size, void* d_ws, size_t ws_size,
                              hipStream_t stream)
{
    const float* x     = (const float*)d_in[0];
    const float* edge  = (const float*)d_in[1];
    const float* initW = (const float*)d_in[2];
    const float* initb = (const float*)d_in[3];
    const float* Wq    = (const float*)d_in[4];
    const float* Wk    = (const float*)d_in[5];
    const float* Wv    = (const float*)d_in[6];
    const float* Wo    = (const float*)d_in[7];
    const float* eW1   = (const float*)d_in[8];
    const float* eb1   = (const float*)d_in[9];
    const float* eW2   = (const float*)d_in[10];
    const float* eb2   = (const float*)d_in[11];
    const float* eW3   = (const float*)d_in[12];
    const float* eb3   = (const float*)d_in[13];
    const float* bn1g  = (const float*)d_in[14];
    const float* bn1b  = (const float*)d_in[15];
    const float* ffW1  = (const float*)d_in[16];
    const float* ffb1  = (const float*)d_in[17];
    const float* ffW2  = (const float*)d_in[18];
    const float* ffb2  = (const float*)d_in[19];
    const float* bn2g  = (const float*)d_in[20];
    const float* bn2b  = (const float*)d_in[21];

    char* ws = (char*)d_ws;
    float* h      = (float*)(ws);                            //  8 MB @0
    float* h2     = (float*)(ws + ((size_t)8  << 20));       //  8 MB @8
    u16*   h_hi   = (u16*)  (ws + ((size_t)16 << 20));       //  4 MB @16 (alias attb_hi)
    u16*   h_lo   = (u16*)  (ws + ((size_t)20 << 20));       //  4 MB @20 (alias attb_lo)
    u16*   qkv_hi = (u16*)  (ws + ((size_t)24 << 20));       // 12 MB @24 (alias ff_hi 8MB)
    u16*   qkv_lo = (u16*)  (ws + ((size_t)36 << 20));       // 12 MB @36 (alias ff_lo 8MB)
    float* stats  = (float*)(ws + ((size_t)48 << 20));       //  2 KB @48
    float* lut    = (float*)(ws + ((size_t)48 << 20) + 4096);// ~131 KB
    u16*   Wt     = (u16*)  (ws + ((size_t)49 << 20));       //  6 MB @49
    u16*   bias   = (u16*)  (ws + ((size_t)56 << 20));       // 64 MB @56 (end 120 MB)
    u16*   attb_hi = h_hi;
    u16*   attb_lo = h_lo;
    u16*   ff_hi   = qkv_hi;
    u16*   ff_lo   = qkv_lo;
    float* outh  = (float*)d_out;
    float* outg  = outh + (size_t)MROWS * DDIM;

    wsplit_kernel<<<6144, 256, 0, stream>>>(Wq, Wk, Wv, Wo, ffW1, ffW2, Wt);
    init_embed_kernel<<<MROWS, 256, 0, stream>>>(x, initW, initb, h, h_hi, h_lo);
    build_lut_kernel<<<17, 256, 0, stream>>>(eW1, eb1, eW2, eb2, eW3, eb3, lut);
    edge_bias_kernel<<<(BB * NNN * NNN) / 256, 256, 0, stream>>>(edge, lut, bias);

    for (int l = 0; l < 3; ++l) {
        u16* WL = Wt + (size_t)l * WT_LSTR;
        // QKV projection -> split qkv
        gemm2_kernel<<<dim3(12, 64), 256, 0, stream>>>(
            h_hi, h_lo, 256, WL, WL + 196608, 768,
            nullptr, qkv_hi, qkv_lo, nullptr, 0, nullptr);
        // fused MFMA attention -> split attb (overwrites h_hi/h_lo region)
        attn_mfma_kernel<<<512, 512, 0, stream>>>(
            qkv_hi, qkv_lo, (l == 0) ? bias : (const u16*)nullptr, attb_hi, attb_lo);
        // Wo projection + residual: h2 = h + attb @ Wo
        gemm2_kernel<<<dim3(4, 64), 256, 0, stream>>>(
            attb_hi, attb_lo, 256, WL + 393216, WL + 458752, 256,
            h2, nullptr, nullptr, nullptr, 0, h);
        zero_stats_kernel<<<1, 256, 0, stream>>>(stats);
        bn_stats_kernel<<<256, 256, 0, stream>>>(h2, stats);
        bn_apply_kernel<<<1024, 256, 0, stream>>>(
            h2, h, h_hi, h_lo, stats, bn1g + l * 256, bn1b + l * 256);
        // FF1: relu(h @ W1 + b1) -> split ff (overwrites qkv region)
        gemm2_kernel<<<dim3(8, 64), 256, 0, stream>>>(
            h_hi, h_lo, 256, WL + 524288, WL + 655360, 512,
            nullptr, ff_hi, ff_lo, ffb1 + l * 512, 1, nullptr);
        // FF2 + bias + residual: h2 = h + ff @ W2 + b2
        gemm2_kernel<<<dim3(4, 64), 256, 0, stream>>>(
            ff_hi, ff_lo, 512, WL + 786432, WL + 917504, 256,
            h2, nullptr, nullptr, ffb2 + l * 256, 0, h);
        zero_stats_kernel<<<1, 256, 0, stream>>>(stats);
        bn_stats_kernel<<<256, 256, 0, stream>>>(h2, stats);
        if (l == 2)
            bn_apply_kernel<<<1024, 256, 0, stream>>>(
                h2, outh, nullptr, nullptr, stats, bn2g + l * 256, bn2b + l * 256);
        else
            bn_apply_kernel<<<1024, 256, 0, stream>>>(
                h2, h, h_hi, h_lo, stats, bn2g + l * 256, bn2b + l * 256);
    }
    graph_embed_kernel<<<BB, 256, 0, stream>>>(outh, outg);
}

// Round 12
// 680.846 us; speedup vs baseline: 1.2141x; 1.0903x over previous
//
#include <hip/hip_runtime.h>

// Shapes (fixed per reference)
#define BB    16
#define NNN   512
#define DDIM  256
#define HH    8
#define DKK   32
#define FFF   512
#define MROWS 8192   // B*N
#define LUTN  4096

using u16    = unsigned short;
using bf16x8 = __attribute__((ext_vector_type(8))) short;
using f32x4  = __attribute__((ext_vector_type(4))) float;

__device__ __forceinline__ float bf2f(u16 u) { return __uint_as_float(((unsigned)u) << 16); }
__device__ __forceinline__ u16 f2bf(float f) {
    unsigned u = __float_as_uint(f);
    return (u16)((u + 0x7fffu + ((u >> 16) & 1u)) >> 16);  // RNE
}

// ---------------------------------------------------------------------------
// h = x @ init_W + init_b ; also emit h_hi/h_lo bf16 split
__global__ __launch_bounds__(256) void init_embed_kernel(
    const float* __restrict__ x, const float* __restrict__ W,
    const float* __restrict__ b, float* __restrict__ h,
    u16* __restrict__ hhi, u16* __restrict__ hlo)
{
    size_t row = blockIdx.x;
    int c = threadIdx.x;
    float x0 = x[row * 2 + 0], x1 = x[row * 2 + 1];
    float v = x0 * W[c] + x1 * W[DDIM + c] + b[c];
    size_t o = row * DDIM + c;
    h[o] = v;
    u16 hv = f2bf(v);
    hhi[o] = hv;
    hlo[o] = f2bf(v - bf2f(hv));
}

// ---------------------------------------------------------------------------
// One-shot weight transpose + hi/lo split.  Per layer (u16-elem offsets within
// a 1048576-elem layer block):
//   QKVt [768][256]  hi@0       lo@196608
//   Wot  [256][256]  hi@393216  lo@458752
//   FF1t [512][256]  hi@524288  lo@655360
//   FF2t [256][512]  hi@786432  lo@917504
#define WT_LSTR 1048576
__global__ __launch_bounds__(256) void wsplit_kernel(
    const float* __restrict__ Wq, const float* __restrict__ Wk,
    const float* __restrict__ Wv, const float* __restrict__ Wo,
    const float* __restrict__ ffW1, const float* __restrict__ ffW2,
    u16* __restrict__ Wt)
{
    int fid = blockIdx.x * 256 + threadIdx.x;   // 3 * 524288 total
    int l = fid >> 19, r = fid & 524287;
    u16* base = Wt + (size_t)l * WT_LSTR;
    float v; int off_hi, off_lo;
    if (r < 196608) {                 // QKVt: n = r>>8, k = r&255
        int n = r >> 8, k = r & 255;
        int mat = n >> 8, hd = (n & 255) >> 5, dk = n & 31;
        const float* Wsel = (mat == 0) ? Wq : ((mat == 1) ? Wk : Wv);
        v = Wsel[(((size_t)l * HH + hd) * DDIM + k) * DKK + dk];
        off_hi = r; off_lo = r + 196608;
    } else if (r < 262144) {          // Wot
        int r2 = r - 196608;
        int n = r2 >> 8, k = r2 & 255;
        int hd = k >> 5, dk = k & 31;
        v = Wo[(((size_t)l * HH + hd) * DKK + dk) * DDIM + n];
        off_hi = 393216 + r2; off_lo = 458752 + r2;
    } else if (r < 393216) {          // FF1t
        int r3 = r - 262144;
        int n = r3 >> 8, k = r3 & 255;
        v = ffW1[((size_t)l * DDIM + k) * FFF + n];
        off_hi = 524288 + r3; off_lo = 655360 + r3;
    } else {                          // FF2t
        int r4 = r - 393216;
        int n = r4 >> 9, k = r4 & 511;
        v = ffW2[((size_t)l * FFF + k) * DDIM + n];
        off_hi = 786432 + r4; off_lo = 917504 + r4;
    }
    u16 hv = f2bf(v);
    base[off_hi] = hv;
    base[off_lo] = f2bf(v - bf2f(hv));
}

// ---------------------------------------------------------------------------
// Edge MLP is a scalar->R^8 piecewise-linear function: build a LUT once.
__global__ __launch_bounds__(256) void build_lut_kernel(
    const float* __restrict__ eW1, const float* __restrict__ eb1,
    const float* __restrict__ eW2, const float* __restrict__ eb2,
    const float* __restrict__ eW3, const float* __restrict__ eb3,
    float* __restrict__ lut)  // (LUTN+1) x 8
{
    int i = blockIdx.x * 256 + threadIdx.x;
    if (i > LUTN) return;
    float e = (float)i * (1.0f / LUTN);
    float t1[16], t2[16];
    #pragma unroll
    for (int a = 0; a < 16; ++a) t1[a] = fmaxf(e * eW1[a] + eb1[a], 0.0f);
    #pragma unroll
    for (int j = 0; j < 16; ++j) {
        float s = eb2[j];
        #pragma unroll
        for (int a = 0; a < 16; ++a) s += t1[a] * eW2[a * 16 + j];
        t2[j] = fmaxf(s, 0.0f);
    }
    #pragma unroll
    for (int hd = 0; hd < 8; ++hd) {
        float s = eb3[hd];
        #pragma unroll
        for (int j = 0; j < 16; ++j) s += t2[j] * eW3[j * 8 + hd];
        lut[(size_t)i * 8 + hd] = s;
    }
}

// bias[hd][b][i][j] (bf16) = lerp(LUT, edge[b,i,j])
__global__ __launch_bounds__(256) void edge_bias_kernel(
    const float* __restrict__ edge, const float* __restrict__ lut,
    u16* __restrict__ bout)
{
    size_t idx = (size_t)blockIdx.x * 256 + threadIdx.x;
    float e = edge[idx];
    float f = e * (float)LUTN;
    f = fminf(fmaxf(f, 0.0f), (float)LUTN - 0.0001f);
    int i0 = (int)f;
    float fr = f - (float)i0;
    const float4* r = (const float4*)(lut + (size_t)i0 * 8);
    float4 a0 = r[0], a1 = r[1], b0 = r[2], b1 = r[3];
    float o[8];
    o[0] = a0.x + fr * (b0.x - a0.x);
    o[1] = a0.y + fr * (b0.y - a0.y);
    o[2] = a0.z + fr * (b0.z - a0.z);
    o[3] = a0.w + fr * (b0.w - a0.w);
    o[4] = a1.x + fr * (b1.x - a1.x);
    o[5] = a1.y + fr * (b1.y - a1.y);
    o[6] = a1.z + fr * (b1.z - a1.z);
    o[7] = a1.w + fr * (b1.w - a1.w);
    #pragma unroll
    for (int hd = 0; hd < 8; ++hd)
        bout[(size_t)hd * (size_t)BB * NNN * NNN + idx] = f2bf(o[hd]);
}

// ---------------------------------------------------------------------------
// GEMM v2: inputs PRE-SPLIT bf16 (A [M][K] hi/lo, Bt [N][K] hi/lo transposed).
// C = Ah*Bh + Ah*Bl + Al*Bh (f32-equivalent). Tile 128x64, BK=64, 4 waves.
__global__ __launch_bounds__(256, 2) void gemm2_kernel(
    const u16* __restrict__ Ah_g, const u16* __restrict__ Al_g, int K,
    const u16* __restrict__ Bth, const u16* __restrict__ Btl, int N,
    float* __restrict__ Cf,
    u16* __restrict__ Chi, u16* __restrict__ Clo,
    const float* __restrict__ bias, int relu,
    const float* __restrict__ res)
{
    __shared__ __align__(16) u16 Ah[128][72];   // 144B rows: 16B-aligned, 2-way max
    __shared__ __align__(16) u16 Al[128][72];
    int m0 = blockIdx.y * 128, n0 = blockIdx.x * 64;
    int tid = threadIdx.x, lid = tid & 63, wid = tid >> 6;
    int wm = wid >> 1, wn = wid & 1;
    int l15 = lid & 15, l4 = lid >> 4;

    f32x4 acc[4][2] = {};

    for (int k0 = 0; k0 < K; k0 += 64) {
        // stage A hi/lo: 128x64 bf16 each (pure copies, no conversion)
        #pragma unroll
        for (int j = 0; j < 4; ++j) {
            int c = tid + 256 * j;          // 1024 chunks of 8 elems
            int row = c >> 3, col8 = c & 7;
            bf16x8 vh = *(const bf16x8*)&Ah_g[(size_t)(m0 + row) * K + k0 + col8 * 8];
            bf16x8 vl = *(const bf16x8*)&Al_g[(size_t)(m0 + row) * K + k0 + col8 * 8];
            *(bf16x8*)&Ah[row][col8 * 8] = vh;
            *(bf16x8*)&Al[row][col8 * 8] = vl;
        }
        __syncthreads();
        #pragma unroll
        for (int ks = 0; ks < 2; ++ks) {
            int ko = ks * 32;
            bf16x8 afh[4], afl[4], bfh[2], bfl[2];
            #pragma unroll
            for (int mi = 0; mi < 4; ++mi) {
                afh[mi] = *(const bf16x8*)&Ah[wm * 64 + mi * 16 + l15][ko + l4 * 8];
                afl[mi] = *(const bf16x8*)&Al[wm * 64 + mi * 16 + l15][ko + l4 * 8];
            }
            #pragma unroll
            for (int ni = 0; ni < 2; ++ni) {
                size_t brow = (size_t)(n0 + wn * 32 + ni * 16 + l15) * K + k0 + ko + l4 * 8;
                bfh[ni] = *(const bf16x8*)&Bth[brow];
                bfl[ni] = *(const bf16x8*)&Btl[brow];
            }
            #pragma unroll
            for (int mi = 0; mi < 4; ++mi)
                #pragma unroll
                for (int ni = 0; ni < 2; ++ni) {
                    acc[mi][ni] = __builtin_amdgcn_mfma_f32_16x16x32_bf16(
                        afh[mi], bfh[ni], acc[mi][ni], 0, 0, 0);
                    acc[mi][ni] = __builtin_amdgcn_mfma_f32_16x16x32_bf16(
                        afh[mi], bfl[ni], acc[mi][ni], 0, 0, 0);
                    acc[mi][ni] = __builtin_amdgcn_mfma_f32_16x16x32_bf16(
                        afl[mi], bfh[ni], acc[mi][ni], 0, 0, 0);
                }
        }
        __syncthreads();
    }
    // epilogue
    #pragma unroll
    for (int mi = 0; mi < 4; ++mi) {
        #pragma unroll
        for (int ni = 0; ni < 2; ++ni) {
            #pragma unroll
            for (int r = 0; r < 4; ++r) {
                int row = m0 + wm * 64 + mi * 16 + l4 * 4 + r;
                int col = n0 + wn * 32 + ni * 16 + l15;
                float v = acc[mi][ni][r];
                if (bias) v += bias[col];
                if (relu) v = fmaxf(v, 0.0f);
                if (res)  v += res[(size_t)row * N + col];
                size_t o = (size_t)row * N + col;
                if (Cf) Cf[o] = v;
                if (Chi) {
                    u16 hv = f2bf(v);
                    Chi[o] = hv;
                    Clo[o] = f2bf(v - bf2f(hv));
                }
            }
        }
    }
}

// ---------------------------------------------------------------------------
// Flash attention v4: 256 threads / 4 waves, 128 q-rows per block (32/wave),
// KV streamed in 4 tiles of 128 with online softmax (m/l rescale in f32).
// Score tile per wave = 32q x 128kv = 64 acc VGPRs (vs v3's 128 -> no spill
// pressure; v1-style 256-thread blocks had provably clean WRITE_SIZE).
// Scores split-bf16 (Qh·Kh + Ql·Kh + Qh·Kl); P bf16; V hi only; O accum f32.
__global__ __launch_bounds__(256, 2) void attn_flash_kernel(
    const u16* __restrict__ qkv_hi, const u16* __restrict__ qkv_lo,
    const u16* __restrict__ bias,
    u16* __restrict__ attb_hi, u16* __restrict__ attb_lo)
{
    __shared__ __align__(16) u16 Kh[128][40];     // 10 KB
    __shared__ __align__(16) u16 Kl[128][40];     // 10 KB
    __shared__ __align__(16) u16 Vt[32][136];     // 8.5 KB (V^T for the tile)
    __shared__ __align__(16) u16 Pw[4][16][136];  // 17 KB per-wave P (qf-reused)
    int wg = blockIdx.x;
    int logical = (wg & 7) * 64 + (wg >> 3);   // bijective (512 % 8 == 0)
    int qc = logical & 3, hd = (logical >> 2) & 7, b = logical >> 5;
    int tid = threadIdx.x, lid = tid & 63, w = tid >> 6;
    int l15 = lid & 15, l4 = lid >> 4;

    const u16* baseh = qkv_hi + (size_t)b * 512 * 768;
    const u16* basel = qkv_lo + (size_t)b * 512 * 768;

    int q0 = qc * 128 + w * 32;   // wave's first q row
    // Q frags (qf=0,1): row = q0 + qf*16 + l15, k = l4*8..l4*8+7
    bf16x8 qh[2], ql[2];
    #pragma unroll
    for (int qf = 0; qf < 2; ++qf) {
        size_t qrow = (size_t)(q0 + qf * 16 + l15) * 768 + hd * 32 + l4 * 8;
        qh[qf] = *(const bf16x8*)&baseh[qrow];
        ql[qf] = *(const bf16x8*)&basel[qrow];
    }

    f32x4 oacc[2][2] = {};          // [qf][dk-frag]
    float mrow[2][4], lrow[2][4];   // [qf][r] for rows l4*4+r
    #pragma unroll
    for (int qf = 0; qf < 2; ++qf)
        #pragma unroll
        for (int r = 0; r < 4; ++r) { mrow[qf][r] = -1e30f; lrow[qf][r] = 0.0f; }

    const float scale = 0.17677669529663687f;  // 1/sqrt(32)

    for (int kt = 0; kt < 4; ++kt) {
        __syncthreads();   // all waves done reading previous tile
        // stage KV tile (128 rows): K hi/lo + V^T
        #pragma unroll
        for (int it = 0; it < 4; ++it) {
            int idx = tid + 256 * it;       // 0..1023
            int n = idx >> 3, c4 = idx & 7;
            size_t grow = (size_t)(kt * 128 + n) * 768 + 256 + hd * 32 + c4 * 4;
            ushort4 kh4 = *(const ushort4*)&baseh[grow];
            ushort4 kl4 = *(const ushort4*)&basel[grow];
            ushort4 vh4 = *(const ushort4*)&baseh[grow + 256];   // V block
            *(ushort4*)&Kh[n][c4 * 4] = kh4;
            *(ushort4*)&Kl[n][c4 * 4] = kl4;
            Vt[c4 * 4 + 0][n] = vh4.x;
            Vt[c4 * 4 + 1][n] = vh4.y;
            Vt[c4 * 4 + 2][n] = vh4.z;
            Vt[c4 * 4 + 3][n] = vh4.w;
        }
        __syncthreads();

        // scores for this tile: sacc[qf][ct] (2 x 8 f32x4 = 64 VGPR)
        f32x4 sacc[2][8];
        #pragma unroll
        for (int ct = 0; ct < 8; ++ct) {
            bf16x8 bh = *(const bf16x8*)&Kh[ct * 16 + l15][l4 * 8];
            bf16x8 bl = *(const bf16x8*)&Kl[ct * 16 + l15][l4 * 8];
            #pragma unroll
            for (int qf = 0; qf < 2; ++qf) {
                f32x4 z = {0.0f, 0.0f, 0.0f, 0.0f};
                z = __builtin_amdgcn_mfma_f32_16x16x32_bf16(qh[qf], bh, z, 0, 0, 0);
                z = __builtin_amdgcn_mfma_f32_16x16x32_bf16(ql[qf], bh, z, 0, 0, 0);
                sacc[qf][ct] = __builtin_amdgcn_mfma_f32_16x16x32_bf16(qh[qf], bl, z, 0, 0, 0);
            }
        }

        // scale + bias
        if (bias) {
            #pragma unroll
            for (int qf = 0; qf < 2; ++qf) {
                size_t brow0 = (((size_t)hd * BB + b) * NNN + q0 + qf * 16 + l4 * 4) * NNN
                               + kt * 128 + l15;
                #pragma unroll
                for (int ct = 0; ct < 8; ++ct)
                    #pragma unroll
                    for (int r = 0; r < 4; ++r)
                        sacc[qf][ct][r] = sacc[qf][ct][r] * scale +
                            bf2f(bias[brow0 + (size_t)r * NNN + ct * 16]);
            }
        } else {
            #pragma unroll
            for (int qf = 0; qf < 2; ++qf)
                #pragma unroll
                for (int ct = 0; ct < 8; ++ct)
                    #pragma unroll
                    for (int r = 0; r < 4; ++r)
                        sacc[qf][ct][r] *= scale;
        }

        // online softmax update + P + rescale O
        #pragma unroll
        for (int qf = 0; qf < 2; ++qf) {
            #pragma unroll
            for (int r = 0; r < 4; ++r) {
                float pm = sacc[qf][0][r];
                #pragma unroll
                for (int ct = 1; ct < 8; ++ct) pm = fmaxf(pm, sacc[qf][ct][r]);
                #pragma unroll
                for (int msk = 1; msk < 16; msk <<= 1) pm = fmaxf(pm, __shfl_xor(pm, msk));
                float mnew = fmaxf(mrow[qf][r], pm);
                float corr = __expf(mrow[qf][r] - mnew);
                mrow[qf][r] = mnew;
                float ls = 0.0f;
                #pragma unroll
                for (int ct = 0; ct < 8; ++ct) {
                    float p = __expf(sacc[qf][ct][r] - mnew);
                    sacc[qf][ct][r] = p;
                    ls += p;
                }
                #pragma unroll
                for (int msk = 1; msk < 16; msk <<= 1) ls += __shfl_xor(ls, msk);
                lrow[qf][r] = lrow[qf][r] * corr + ls;
                oacc[qf][0][r] *= corr;
                oacc[qf][1][r] *= corr;
            }
        }

        // PV per qf through per-wave P buffer (intra-wave LDS ordering)
        #pragma unroll
        for (int qf = 0; qf < 2; ++qf) {
            #pragma unroll
            for (int ct = 0; ct < 8; ++ct)
                #pragma unroll
                for (int r = 0; r < 4; ++r)
                    Pw[w][l4 * 4 + r][ct * 16 + l15] = f2bf(sacc[qf][ct][r]);
            #pragma unroll
            for (int ks = 0; ks < 4; ++ks) {
                bf16x8 pa = *(const bf16x8*)&Pw[w][l15][ks * 32 + l4 * 8];
                #pragma unroll
                for (int dc = 0; dc < 2; ++dc) {
                    bf16x8 vb = *(const bf16x8*)&Vt[dc * 16 + l15][ks * 32 + l4 * 8];
                    oacc[qf][dc] = __builtin_amdgcn_mfma_f32_16x16x32_bf16(
                        pa, vb, oacc[qf][dc], 0, 0, 0);
                }
            }
        }
    }

    // epilogue: normalize by lrow, split-write attb
    #pragma unroll
    for (int qf = 0; qf < 2; ++qf)
        #pragma unroll
        for (int dc = 0; dc < 2; ++dc)
            #pragma unroll
            for (int r = 0; r < 4; ++r) {
                float o = oacc[qf][dc][r] / lrow[qf][r];
                size_t oi = ((size_t)b * NNN + q0 + qf * 16 + l4 * 4 + r) * DDIM
                            + hd * 32 + dc * 16 + l15;
                u16 hv = f2bf(o);
                attb_hi[oi] = hv;
                attb_lo[oi] = f2bf(o - bf2f(hv));
            }
}

// ---------------------------------------------------------------------------
__global__ void zero_stats_kernel(float* stats)
{
    stats[threadIdx.x] = 0.0f;
    stats[256 + threadIdx.x] = 0.0f;
}

__global__ __launch_bounds__(256) void bn_stats_kernel(
    const float* __restrict__ X, float* __restrict__ stats)
{
    int c = threadIdx.x;
    size_t r0 = (size_t)blockIdx.x * 32;
    float s = 0.0f, ss = 0.0f;
    for (int r = 0; r < 32; ++r) {
        float v = X[(r0 + r) * DDIM + c];
        s += v; ss += v * v;
    }
    atomicAdd(&stats[c], s);
    atomicAdd(&stats[256 + c], ss);
}

__global__ __launch_bounds__(256) void bn_apply_kernel(
    const float* __restrict__ X, float* __restrict__ Y,
    u16* __restrict__ Yhi, u16* __restrict__ Ylo,
    const float* __restrict__ stats,
    const float* __restrict__ g, const float* __restrict__ bb)
{
    int c = threadIdx.x;
    float mean = stats[c] * (1.0f / MROWS);
    float var  = stats[256 + c] * (1.0f / MROWS) - mean * mean;
    float inv  = rsqrtf(var + 1e-5f);
    float gg = g[c] * inv;
    float off = bb[c] - mean * gg;
    size_t r0 = (size_t)blockIdx.x * 8;
    #pragma unroll
    for (int r = 0; r < 8; ++r) {
        size_t o = (r0 + r) * DDIM + c;
        float y = X[o] * gg + off;
        Y[o] = y;
        if (Yhi) {
            u16 hv = f2bf(y);
            Yhi[o] = hv;
            Ylo[o] = f2bf(y - bf2f(hv));
        }
    }
}

__global__ __launch_bounds__(256) void graph_embed_kernel(
    const float* __restrict__ outh, float* __restrict__ outg)
{
    int c = threadIdx.x, b = blockIdx.x;
    float s = 0.0f;
    for (int n = 0; n < NNN; ++n)
        s += outh[((size_t)b * NNN + n) * DDIM + c];
    outg[b * DDIM + c] = s * (1.0f / NNN);
}

// ---------------------------------------------------------------------------
extern "C" void kernel_launch(void* const* d_in, const int* in_sizes, int n_in,
                              void* d_out, int out_size, void* d_ws, size_t ws_size,
                              hipStream_t stream)
{
    const float* x     = (const float*)d_in[0];
    const float* edge  = (const float*)d_in[1];
    const float* initW = (const float*)d_in[2];
    const float* initb = (const float*)d_in[3];
    const float* Wq    = (const float*)d_in[4];
    const float* Wk    = (const float*)d_in[5];
    const float* Wv    = (const float*)d_in[6];
    const float* Wo    = (const float*)d_in[7];
    const float* eW1   = (const float*)d_in[8];
    const float* eb1   = (const float*)d_in[9];
    const float* eW2   = (const float*)d_in[10];
    const float* eb2   = (const float*)d_in[11];
    const float* eW3   = (const float*)d_in[12];
    const float* eb3   = (const float*)d_in[13];
    const float* bn1g  = (const float*)d_in[14];
    const float* bn1b  = (const float*)d_in[15];
    const float* ffW1  = (const float*)d_in[16];
    const float* ffb1  = (const float*)d_in[17];
    const float* ffW2  = (const float*)d_in[18];
    const float* ffb2  = (const float*)d_in[19];
    const float* bn2g  = (const float*)d_in[20];
    const float* bn2b  = (const float*)d_in[21];

    char* ws = (char*)d_ws;
    float* h      = (float*)(ws);                            //  8 MB @0
    float* h2     = (float*)(ws + ((size_t)8  << 20));       //  8 MB @8
    u16*   h_hi   = (u16*)  (ws + ((size_t)16 << 20));       //  4 MB @16 (alias attb_hi)
    u16*   h_lo   = (u16*)  (ws + ((size_t)20 << 20));       //  4 MB @20 (alias attb_lo)
    u16*   qkv_hi = (u16*)  (ws + ((size_t)24 << 20));       // 12 MB @24 (alias ff_hi 8MB)
    u16*   qkv_lo = (u16*)  (ws + ((size_t)36 << 20));       // 12 MB @36 (alias ff_lo 8MB)
    float* stats  = (float*)(ws + ((size_t)48 << 20));       //  2 KB @48
    float* lut    = (float*)(ws + ((size_t)48 << 20) + 4096);// ~131 KB
    u16*   Wt     = (u16*)  (ws + ((size_t)49 << 20));       //  6 MB @49
    u16*   bias   = (u16*)  (ws + ((size_t)56 << 20));       // 64 MB @56 (end 120 MB)
    u16*   attb_hi = h_hi;
    u16*   attb_lo = h_lo;
    u16*   ff_hi   = qkv_hi;
    u16*   ff_lo   = qkv_lo;
    float* outh  = (float*)d_out;
    float* outg  = outh + (size_t)MROWS * DDIM;

    wsplit_kernel<<<6144, 256, 0, stream>>>(Wq, Wk, Wv, Wo, ffW1, ffW2, Wt);
    init_embed_kernel<<<MROWS, 256, 0, stream>>>(x, initW, initb, h, h_hi, h_lo);
    build_lut_kernel<<<17, 256, 0, stream>>>(eW1, eb1, eW2, eb2, eW3, eb3, lut);
    edge_bias_kernel<<<(BB * NNN * NNN) / 256, 256, 0, stream>>>(edge, lut, bias);

    for (int l = 0; l < 3; ++l) {
        u16* WL = Wt + (size_t)l * WT_LSTR;
        // QKV projection -> split qkv
        gemm2_kernel<<<dim3(12, 64), 256, 0, stream>>>(
            h_hi, h_lo, 256, WL, WL + 196608, 768,
            nullptr, qkv_hi, qkv_lo, nullptr, 0, nullptr);
        // flash MFMA attention -> split attb (overwrites h_hi/h_lo region)
        attn_flash_kernel<<<512, 256, 0, stream>>>(
            qkv_hi, qkv_lo, (l == 0) ? bias : (const u16*)nullptr, attb_hi, attb_lo);
        // Wo projection + residual: h2 = h + attb @ Wo
        gemm2_kernel<<<dim3(4, 64), 256, 0, stream>>>(
            attb_hi, attb_lo, 256, WL + 393216, WL + 458752, 256,
            h2, nullptr, nullptr, nullptr, 0, h);
        zero_stats_kernel<<<1, 256, 0, stream>>>(stats);
        bn_stats_kernel<<<256, 256, 0, stream>>>(h2, stats);
        bn_apply_kernel<<<1024, 256, 0, stream>>>(
            h2, h, h_hi, h_lo, stats, bn1g + l * 256, bn1b + l * 256);
        // FF1: relu(h @ W1 + b1) -> split ff (overwrites qkv region)
        gemm2_kernel<<<dim3(8, 64), 256, 0, stream>>>(
            h_hi, h_lo, 256, WL + 524288, WL + 655360, 512,
            nullptr, ff_hi, ff_lo, ffb1 + l * 512, 1, nullptr);
        // FF2 + bias + residual: h2 = h + ff @ W2 + b2
        gemm2_kernel<<<dim3(4, 64), 256, 0, stream>>>(
            ff_hi, ff_lo, 512, WL + 786432, WL + 917504, 256,
            h2, nullptr, nullptr, ffb2 + l * 256, 0, h);
        zero_stats_kernel<<<1, 256, 0, stream>>>(stats);
        bn_stats_kernel<<<256, 256, 0, stream>>>(h2, stats);
        if (l == 2)
            bn_apply_kernel<<<1024, 256, 0, stream>>>(
                h2, outh, nullptr, nullptr, stats, bn2g + l * 256, bn2b + l * 256);
        else
            bn_apply_kernel<<<1024, 256, 0, stream>>>(
                h2, h, h_hi, h_lo, stats, bn2g + l * 256, bn2b + l * 256);
    }
    graph_embed_kernel<<<BB, 256, 0, stream>>>(outh, outg);
}

// Round 13
// 624.384 us; speedup vs baseline: 1.3239x; 1.0904x over previous
//
#include <hip/hip_runtime.h>

// Shapes (fixed per reference)
#define BB    16
#define NNN   512
#define DDIM  256
#define HH    8
#define DKK   32
#define FFF   512
#define MROWS 8192   // B*N
#define LUTN  4096

using u16    = unsigned short;
using bf16x8 = __attribute__((ext_vector_type(8))) short;
using f32x4  = __attribute__((ext_vector_type(4))) float;

__device__ __forceinline__ float bf2f(u16 u) { return __uint_as_float(((unsigned)u) << 16); }
__device__ __forceinline__ u16 f2bf(float f) {
    unsigned u = __float_as_uint(f);
    return (u16)((u + 0x7fffu + ((u >> 16) & 1u)) >> 16);  // RNE
}

// ---------------------------------------------------------------------------
// h = x @ init_W + init_b ; also emit h_hi/h_lo bf16 split
__global__ __launch_bounds__(256) void init_embed_kernel(
    const float* __restrict__ x, const float* __restrict__ W,
    const float* __restrict__ b, float* __restrict__ h,
    u16* __restrict__ hhi, u16* __restrict__ hlo)
{
    size_t row = blockIdx.x;
    int c = threadIdx.x;
    float x0 = x[row * 2 + 0], x1 = x[row * 2 + 1];
    float v = x0 * W[c] + x1 * W[DDIM + c] + b[c];
    size_t o = row * DDIM + c;
    h[o] = v;
    u16 hv = f2bf(v);
    hhi[o] = hv;
    hlo[o] = f2bf(v - bf2f(hv));
}

// ---------------------------------------------------------------------------
// One-shot weight transpose + hi/lo split.  Per layer (u16-elem offsets within
// a 1048576-elem layer block):
//   QKVt [768][256]  hi@0       lo@196608
//   Wot  [256][256]  hi@393216  lo@458752
//   FF1t [512][256]  hi@524288  lo@655360
//   FF2t [256][512]  hi@786432  lo@917504
#define WT_LSTR 1048576
__global__ __launch_bounds__(256) void wsplit_kernel(
    const float* __restrict__ Wq, const float* __restrict__ Wk,
    const float* __restrict__ Wv, const float* __restrict__ Wo,
    const float* __restrict__ ffW1, const float* __restrict__ ffW2,
    u16* __restrict__ Wt)
{
    int fid = blockIdx.x * 256 + threadIdx.x;   // 3 * 524288 total
    int l = fid >> 19, r = fid & 524287;
    u16* base = Wt + (size_t)l * WT_LSTR;
    float v; int off_hi, off_lo;
    if (r < 196608) {                 // QKVt: n = r>>8, k = r&255
        int n = r >> 8, k = r & 255;
        int mat = n >> 8, hd = (n & 255) >> 5, dk = n & 31;
        const float* Wsel = (mat == 0) ? Wq : ((mat == 1) ? Wk : Wv);
        v = Wsel[(((size_t)l * HH + hd) * DDIM + k) * DKK + dk];
        off_hi = r; off_lo = r + 196608;
    } else if (r < 262144) {          // Wot
        int r2 = r - 196608;
        int n = r2 >> 8, k = r2 & 255;
        int hd = k >> 5, dk = k & 31;
        v = Wo[(((size_t)l * HH + hd) * DKK + dk) * DDIM + n];
        off_hi = 393216 + r2; off_lo = 458752 + r2;
    } else if (r < 393216) {          // FF1t
        int r3 = r - 262144;
        int n = r3 >> 8, k = r3 & 255;
        v = ffW1[((size_t)l * DDIM + k) * FFF + n];
        off_hi = 524288 + r3; off_lo = 655360 + r3;
    } else {                          // FF2t
        int r4 = r - 393216;
        int n = r4 >> 9, k = r4 & 511;
        v = ffW2[((size_t)l * FFF + k) * DDIM + n];
        off_hi = 786432 + r4; off_lo = 917504 + r4;
    }
    u16 hv = f2bf(v);
    base[off_hi] = hv;
    base[off_lo] = f2bf(v - bf2f(hv));
}

// ---------------------------------------------------------------------------
// Edge MLP LUT. Round-12: build_lut was 80us — 17 blocks, each thread doing
// ~440 uniform HBM loads + serial FMA chain = latency-bound. Fix: stage the
// 440 weight floats in LDS once per block, compute from LDS.
__global__ __launch_bounds__(256) void build_lut_kernel(
    const float* __restrict__ eW1, const float* __restrict__ eb1,
    const float* __restrict__ eW2, const float* __restrict__ eb2,
    const float* __restrict__ eW3, const float* __restrict__ eb3,
    float* __restrict__ lut)  // (LUTN+1) x 8
{
    __shared__ float sm[440];  // W1@0 b1@16 W2@32 b2@288 W3@304 b3@432
    int t = threadIdx.x;
    if (t < 16) { sm[t] = eW1[t]; sm[16 + t] = eb1[t]; sm[288 + t] = eb2[t]; }
    if (t < 256) sm[32 + t] = eW2[t];
    if (t < 128) sm[304 + t] = eW3[t];
    if (t < 8)   sm[432 + t] = eb3[t];
    __syncthreads();
    int i = blockIdx.x * 256 + t;
    if (i > LUTN) return;
    float e = (float)i * (1.0f / LUTN);
    float t1[16], t2[16];
    #pragma unroll
    for (int a = 0; a < 16; ++a) t1[a] = fmaxf(e * sm[a] + sm[16 + a], 0.0f);
    #pragma unroll
    for (int j = 0; j < 16; ++j) {
        float s = sm[288 + j];
        #pragma unroll
        for (int a = 0; a < 16; ++a) s += t1[a] * sm[32 + a * 16 + j];
        t2[j] = fmaxf(s, 0.0f);
    }
    #pragma unroll
    for (int hd = 0; hd < 8; ++hd) {
        float s = sm[432 + hd];
        #pragma unroll
        for (int j = 0; j < 16; ++j) s += t2[j] * sm[304 + j * 8 + hd];
        lut[(size_t)i * 8 + hd] = s;
    }
}

// bias[hd][b][i][j] (bf16) = lerp(LUT, edge[b,i,j])
__global__ __launch_bounds__(256) void edge_bias_kernel(
    const float* __restrict__ edge, const float* __restrict__ lut,
    u16* __restrict__ bout)
{
    size_t idx = (size_t)blockIdx.x * 256 + threadIdx.x;
    float e = edge[idx];
    float f = e * (float)LUTN;
    f = fminf(fmaxf(f, 0.0f), (float)LUTN - 0.0001f);
    int i0 = (int)f;
    float fr = f - (float)i0;
    const float4* r = (const float4*)(lut + (size_t)i0 * 8);
    float4 a0 = r[0], a1 = r[1], b0 = r[2], b1 = r[3];
    float o[8];
    o[0] = a0.x + fr * (b0.x - a0.x);
    o[1] = a0.y + fr * (b0.y - a0.y);
    o[2] = a0.z + fr * (b0.z - a0.z);
    o[3] = a0.w + fr * (b0.w - a0.w);
    o[4] = a1.x + fr * (b1.x - a1.x);
    o[5] = a1.y + fr * (b1.y - a1.y);
    o[6] = a1.z + fr * (b1.z - a1.z);
    o[7] = a1.w + fr * (b1.w - a1.w);
    #pragma unroll
    for (int hd = 0; hd < 8; ++hd)
        bout[(size_t)hd * (size_t)BB * NNN * NNN + idx] = f2bf(o[hd]);
}

// ---------------------------------------------------------------------------
// GEMM v3: pre-split bf16 inputs; optional fused BN-stats (per-column sum &
// sumsq atomically accumulated into bnstats[0..255]=sum, [256..511]=sumsq).
// Stats reduced via LDS tree reusing the Ah buffer after the final barrier.
__global__ __launch_bounds__(256, 2) void gemm2_kernel(
    const u16* __restrict__ Ah_g, const u16* __restrict__ Al_g, int K,
    const u16* __restrict__ Bth, const u16* __restrict__ Btl, int N,
    float* __restrict__ Cf,
    u16* __restrict__ Chi, u16* __restrict__ Clo,
    const float* __restrict__ bias, int relu,
    const float* __restrict__ res,
    float* __restrict__ bnstats)
{
    __shared__ __align__(16) u16 Ah[128][72];   // 144B rows: 16B-aligned, 2-way max
    __shared__ __align__(16) u16 Al[128][72];
    int m0 = blockIdx.y * 128, n0 = blockIdx.x * 64;
    int tid = threadIdx.x, lid = tid & 63, wid = tid >> 6;
    int wm = wid >> 1, wn = wid & 1;
    int l15 = lid & 15, l4 = lid >> 4;

    f32x4 acc[4][2] = {};

    for (int k0 = 0; k0 < K; k0 += 64) {
        // stage A hi/lo: 128x64 bf16 each (pure copies, no conversion)
        #pragma unroll
        for (int j = 0; j < 4; ++j) {
            int c = tid + 256 * j;          // 1024 chunks of 8 elems
            int row = c >> 3, col8 = c & 7;
            bf16x8 vh = *(const bf16x8*)&Ah_g[(size_t)(m0 + row) * K + k0 + col8 * 8];
            bf16x8 vl = *(const bf16x8*)&Al_g[(size_t)(m0 + row) * K + k0 + col8 * 8];
            *(bf16x8*)&Ah[row][col8 * 8] = vh;
            *(bf16x8*)&Al[row][col8 * 8] = vl;
        }
        __syncthreads();
        #pragma unroll
        for (int ks = 0; ks < 2; ++ks) {
            int ko = ks * 32;
            bf16x8 afh[4], afl[4], bfh[2], bfl[2];
            #pragma unroll
            for (int mi = 0; mi < 4; ++mi) {
                afh[mi] = *(const bf16x8*)&Ah[wm * 64 + mi * 16 + l15][ko + l4 * 8];
                afl[mi] = *(const bf16x8*)&Al[wm * 64 + mi * 16 + l15][ko + l4 * 8];
            }
            #pragma unroll
            for (int ni = 0; ni < 2; ++ni) {
                size_t brow = (size_t)(n0 + wn * 32 + ni * 16 + l15) * K + k0 + ko + l4 * 8;
                bfh[ni] = *(const bf16x8*)&Bth[brow];
                bfl[ni] = *(const bf16x8*)&Btl[brow];
            }
            #pragma unroll
            for (int mi = 0; mi < 4; ++mi)
                #pragma unroll
                for (int ni = 0; ni < 2; ++ni) {
                    acc[mi][ni] = __builtin_amdgcn_mfma_f32_16x16x32_bf16(
                        afh[mi], bfh[ni], acc[mi][ni], 0, 0, 0);
                    acc[mi][ni] = __builtin_amdgcn_mfma_f32_16x16x32_bf16(
                        afh[mi], bfl[ni], acc[mi][ni], 0, 0, 0);
                    acc[mi][ni] = __builtin_amdgcn_mfma_f32_16x16x32_bf16(
                        afl[mi], bfh[ni], acc[mi][ni], 0, 0, 0);
                }
        }
        __syncthreads();
    }
    // epilogue (+ optional per-column stats partials)
    float psum[2] = {0.0f, 0.0f}, psq[2] = {0.0f, 0.0f};
    #pragma unroll
    for (int mi = 0; mi < 4; ++mi) {
        #pragma unroll
        for (int ni = 0; ni < 2; ++ni) {
            #pragma unroll
            for (int r = 0; r < 4; ++r) {
                int row = m0 + wm * 64 + mi * 16 + l4 * 4 + r;
                int col = n0 + wn * 32 + ni * 16 + l15;
                float v = acc[mi][ni][r];
                if (bias) v += bias[col];
                if (relu) v = fmaxf(v, 0.0f);
                if (res)  v += res[(size_t)row * N + col];
                size_t o = (size_t)row * N + col;
                if (Cf) Cf[o] = v;
                if (Chi) {
                    u16 hv = f2bf(v);
                    Chi[o] = hv;
                    Clo[o] = f2bf(v - bf2f(hv));
                }
                if (bnstats) { psum[ni] += v; psq[ni] += v * v; }
            }
        }
    }
    if (bnstats) {
        // LDS tree-reduce over (wm, l4) per column; Ah reuse is safe post-barrier
        float* red = (float*)&Ah[0][0];   // 1024 floats
        int base = ((((wm * 2 + wn) * 4 + l4) * 16 + l15) * 4);
        __syncthreads();
        #pragma unroll
        for (int ni = 0; ni < 2; ++ni) {
            red[base + ni * 2 + 0] = psum[ni];
            red[base + ni * 2 + 1] = psq[ni];
        }
        __syncthreads();
        if (tid < 128) {
            int col = tid & 63, which = tid >> 6;
            int wn_ = col >> 5, ni_ = (col >> 4) & 1, l15_ = col & 15;
            float s = 0.0f;
            #pragma unroll
            for (int wm_ = 0; wm_ < 2; ++wm_)
                #pragma unroll
                for (int l4_ = 0; l4_ < 4; ++l4_)
                    s += red[((((wm_ * 2 + wn_) * 4 + l4_) * 16 + l15_) * 4) + ni_ * 2 + which];
            atomicAdd(&bnstats[which * 256 + n0 + col], s);
        }
    }
}

// ---------------------------------------------------------------------------
// Flash attention v4 (unchanged from round 12)
__global__ __launch_bounds__(256, 2) void attn_flash_kernel(
    const u16* __restrict__ qkv_hi, const u16* __restrict__ qkv_lo,
    const u16* __restrict__ bias,
    u16* __restrict__ attb_hi, u16* __restrict__ attb_lo)
{
    __shared__ __align__(16) u16 Kh[128][40];
    __shared__ __align__(16) u16 Kl[128][40];
    __shared__ __align__(16) u16 Vt[32][136];
    __shared__ __align__(16) u16 Pw[4][16][136];
    int wg = blockIdx.x;
    int logical = (wg & 7) * 64 + (wg >> 3);   // bijective (512 % 8 == 0)
    int qc = logical & 3, hd = (logical >> 2) & 7, b = logical >> 5;
    int tid = threadIdx.x, lid = tid & 63, w = tid >> 6;
    int l15 = lid & 15, l4 = lid >> 4;

    const u16* baseh = qkv_hi + (size_t)b * 512 * 768;
    const u16* basel = qkv_lo + (size_t)b * 512 * 768;

    int q0 = qc * 128 + w * 32;
    bf16x8 qh[2], ql[2];
    #pragma unroll
    for (int qf = 0; qf < 2; ++qf) {
        size_t qrow = (size_t)(q0 + qf * 16 + l15) * 768 + hd * 32 + l4 * 8;
        qh[qf] = *(const bf16x8*)&baseh[qrow];
        ql[qf] = *(const bf16x8*)&basel[qrow];
    }

    f32x4 oacc[2][2] = {};
    float mrow[2][4], lrow[2][4];
    #pragma unroll
    for (int qf = 0; qf < 2; ++qf)
        #pragma unroll
        for (int r = 0; r < 4; ++r) { mrow[qf][r] = -1e30f; lrow[qf][r] = 0.0f; }

    const float scale = 0.17677669529663687f;

    for (int kt = 0; kt < 4; ++kt) {
        __syncthreads();
        #pragma unroll
        for (int it = 0; it < 4; ++it) {
            int idx = tid + 256 * it;
            int n = idx >> 3, c4 = idx & 7;
            size_t grow = (size_t)(kt * 128 + n) * 768 + 256 + hd * 32 + c4 * 4;
            ushort4 kh4 = *(const ushort4*)&baseh[grow];
            ushort4 kl4 = *(const ushort4*)&basel[grow];
            ushort4 vh4 = *(const ushort4*)&baseh[grow + 256];
            *(ushort4*)&Kh[n][c4 * 4] = kh4;
            *(ushort4*)&Kl[n][c4 * 4] = kl4;
            Vt[c4 * 4 + 0][n] = vh4.x;
            Vt[c4 * 4 + 1][n] = vh4.y;
            Vt[c4 * 4 + 2][n] = vh4.z;
            Vt[c4 * 4 + 3][n] = vh4.w;
        }
        __syncthreads();

        f32x4 sacc[2][8];
        #pragma unroll
        for (int ct = 0; ct < 8; ++ct) {
            bf16x8 bh = *(const bf16x8*)&Kh[ct * 16 + l15][l4 * 8];
            bf16x8 bl = *(const bf16x8*)&Kl[ct * 16 + l15][l4 * 8];
            #pragma unroll
            for (int qf = 0; qf < 2; ++qf) {
                f32x4 z = {0.0f, 0.0f, 0.0f, 0.0f};
                z = __builtin_amdgcn_mfma_f32_16x16x32_bf16(qh[qf], bh, z, 0, 0, 0);
                z = __builtin_amdgcn_mfma_f32_16x16x32_bf16(ql[qf], bh, z, 0, 0, 0);
                sacc[qf][ct] = __builtin_amdgcn_mfma_f32_16x16x32_bf16(qh[qf], bl, z, 0, 0, 0);
            }
        }

        if (bias) {
            #pragma unroll
            for (int qf = 0; qf < 2; ++qf) {
                size_t brow0 = (((size_t)hd * BB + b) * NNN + q0 + qf * 16 + l4 * 4) * NNN
                               + kt * 128 + l15;
                #pragma unroll
                for (int ct = 0; ct < 8; ++ct)
                    #pragma unroll
                    for (int r = 0; r < 4; ++r)
                        sacc[qf][ct][r] = sacc[qf][ct][r] * scale +
                            bf2f(bias[brow0 + (size_t)r * NNN + ct * 16]);
            }
        } else {
            #pragma unroll
            for (int qf = 0; qf < 2; ++qf)
                #pragma unroll
                for (int ct = 0; ct < 8; ++ct)
                    #pragma unroll
                    for (int r = 0; r < 4; ++r)
                        sacc[qf][ct][r] *= scale;
        }

        #pragma unroll
        for (int qf = 0; qf < 2; ++qf) {
            #pragma unroll
            for (int r = 0; r < 4; ++r) {
                float pm = sacc[qf][0][r];
                #pragma unroll
                for (int ct = 1; ct < 8; ++ct) pm = fmaxf(pm, sacc[qf][ct][r]);
                #pragma unroll
                for (int msk = 1; msk < 16; msk <<= 1) pm = fmaxf(pm, __shfl_xor(pm, msk));
                float mnew = fmaxf(mrow[qf][r], pm);
                float corr = __expf(mrow[qf][r] - mnew);
                mrow[qf][r] = mnew;
                float ls = 0.0f;
                #pragma unroll
                for (int ct = 0; ct < 8; ++ct) {
                    float p = __expf(sacc[qf][ct][r] - mnew);
                    sacc[qf][ct][r] = p;
                    ls += p;
                }
                #pragma unroll
                for (int msk = 1; msk < 16; msk <<= 1) ls += __shfl_xor(ls, msk);
                lrow[qf][r] = lrow[qf][r] * corr + ls;
                oacc[qf][0][r] *= corr;
                oacc[qf][1][r] *= corr;
            }
        }

        #pragma unroll
        for (int qf = 0; qf < 2; ++qf) {
            #pragma unroll
            for (int ct = 0; ct < 8; ++ct)
                #pragma unroll
                for (int r = 0; r < 4; ++r)
                    Pw[w][l4 * 4 + r][ct * 16 + l15] = f2bf(sacc[qf][ct][r]);
            #pragma unroll
            for (int ks = 0; ks < 4; ++ks) {
                bf16x8 pa = *(const bf16x8*)&Pw[w][l15][ks * 32 + l4 * 8];
                #pragma unroll
                for (int dc = 0; dc < 2; ++dc) {
                    bf16x8 vb = *(const bf16x8*)&Vt[dc * 16 + l15][ks * 32 + l4 * 8];
                    oacc[qf][dc] = __builtin_amdgcn_mfma_f32_16x16x32_bf16(
                        pa, vb, oacc[qf][dc], 0, 0, 0);
                }
            }
        }
    }

    #pragma unroll
    for (int qf = 0; qf < 2; ++qf)
        #pragma unroll
        for (int dc = 0; dc < 2; ++dc)
            #pragma unroll
            for (int r = 0; r < 4; ++r) {
                float o = oacc[qf][dc][r] / lrow[qf][r];
                size_t oi = ((size_t)b * NNN + q0 + qf * 16 + l4 * 4 + r) * DDIM
                            + hd * 32 + dc * 16 + l15;
                u16 hv = f2bf(o);
                attb_hi[oi] = hv;
                attb_lo[oi] = f2bf(o - bf2f(hv));
            }
}

// ---------------------------------------------------------------------------
__global__ void zero_stats_kernel(float* stats)   // zero all 6 stage buffers
{
    int i = blockIdx.x * 256 + threadIdx.x;
    if (i < 3072) stats[i] = 0.0f;
}

__global__ __launch_bounds__(256) void bn_apply_kernel(
    const float* __restrict__ X, float* __restrict__ Y,
    u16* __restrict__ Yhi, u16* __restrict__ Ylo,
    const float* __restrict__ stats,
    const float* __restrict__ g, const float* __restrict__ bb)
{
    int c = threadIdx.x;
    float mean = stats[c] * (1.0f / MROWS);
    float var  = stats[256 + c] * (1.0f / MROWS) - mean * mean;
    float inv  = rsqrtf(var + 1e-5f);
    float gg = g[c] * inv;
    float off = bb[c] - mean * gg;
    size_t r0 = (size_t)blockIdx.x * 8;
    #pragma unroll
    for (int r = 0; r < 8; ++r) {
        size_t o = (r0 + r) * DDIM + c;
        float y = X[o] * gg + off;
        Y[o] = y;
        if (Yhi) {
            u16 hv = f2bf(y);
            Yhi[o] = hv;
            Ylo[o] = f2bf(y - bf2f(hv));
        }
    }
}

__global__ __launch_bounds__(256) void graph_embed_kernel(
    const float* __restrict__ outh, float* __restrict__ outg)
{
    int c = threadIdx.x, b = blockIdx.x;
    float s = 0.0f;
    for (int n = 0; n < NNN; ++n)
        s += outh[((size_t)b * NNN + n) * DDIM + c];
    outg[b * DDIM + c] = s * (1.0f / NNN);
}

// ---------------------------------------------------------------------------
extern "C" void kernel_launch(void* const* d_in, const int* in_sizes, int n_in,
                              void* d_out, int out_size, void* d_ws, size_t ws_size,
                              hipStream_t stream)
{
    const float* x     = (const float*)d_in[0];
    const float* edge  = (const float*)d_in[1];
    const float* initW = (const float*)d_in[2];
    const float* initb = (const float*)d_in[3];
    const float* Wq    = (const float*)d_in[4];
    const float* Wk    = (const float*)d_in[5];
    const float* Wv    = (const float*)d_in[6];
    const float* Wo    = (const float*)d_in[7];
    const float* eW1   = (const float*)d_in[8];
    const float* eb1   = (const float*)d_in[9];
    const float* eW2   = (const float*)d_in[10];
    const float* eb2   = (const float*)d_in[11];
    const float* eW3   = (const float*)d_in[12];
    const float* eb3   = (const float*)d_in[13];
    const float* bn1g  = (const float*)d_in[14];
    const float* bn1b  = (const float*)d_in[15];
    const float* ffW1  = (const float*)d_in[16];
    const float* ffb1  = (const float*)d_in[17];
    const float* ffW2  = (const float*)d_in[18];
    const float* ffb2  = (const float*)d_in[19];
    const float* bn2g  = (const float*)d_in[20];
    const float* bn2b  = (const float*)d_in[21];

    char* ws = (char*)d_ws;
    float* h      = (float*)(ws);                            //  8 MB @0
    float* h2     = (float*)(ws + ((size_t)8  << 20));       //  8 MB @8
    u16*   h_hi   = (u16*)  (ws + ((size_t)16 << 20));       //  4 MB @16 (alias attb_hi)
    u16*   h_lo   = (u16*)  (ws + ((size_t)20 << 20));       //  4 MB @20 (alias attb_lo)
    u16*   qkv_hi = (u16*)  (ws + ((size_t)24 << 20));       // 12 MB @24 (alias ff_hi 8MB)
    u16*   qkv_lo = (u16*)  (ws + ((size_t)36 << 20));       // 12 MB @36 (alias ff_lo 8MB)
    float* statsA = (float*)(ws + ((size_t)48 << 20));       // 12 KB @48 (6 x 512 f32)
    float* lut    = (float*)(ws + ((size_t)48 << 20) + 16384);// ~131 KB
    u16*   Wt     = (u16*)  (ws + ((size_t)49 << 20));       //  6 MB @49
    u16*   bias   = (u16*)  (ws + ((size_t)56 << 20));       // 64 MB @56 (end 120 MB)
    u16*   attb_hi = h_hi;
    u16*   attb_lo = h_lo;
    u16*   ff_hi   = qkv_hi;
    u16*   ff_lo   = qkv_lo;
    float* outh  = (float*)d_out;
    float* outg  = outh + (size_t)MROWS * DDIM;

    wsplit_kernel<<<6144, 256, 0, stream>>>(Wq, Wk, Wv, Wo, ffW1, ffW2, Wt);
    init_embed_kernel<<<MROWS, 256, 0, stream>>>(x, initW, initb, h, h_hi, h_lo);
    build_lut_kernel<<<17, 256, 0, stream>>>(eW1, eb1, eW2, eb2, eW3, eb3, lut);
    edge_bias_kernel<<<(BB * NNN * NNN) / 256, 256, 0, stream>>>(edge, lut, bias);
    zero_stats_kernel<<<12, 256, 0, stream>>>(statsA);

    for (int l = 0; l < 3; ++l) {
        u16* WL = Wt + (size_t)l * WT_LSTR;
        float* st1 = statsA + (size_t)(l * 2 + 0) * 512;
        float* st2 = statsA + (size_t)(l * 2 + 1) * 512;
        // QKV projection -> split qkv
        gemm2_kernel<<<dim3(12, 64), 256, 0, stream>>>(
            h_hi, h_lo, 256, WL, WL + 196608, 768,
            nullptr, qkv_hi, qkv_lo, nullptr, 0, nullptr, nullptr);
        // flash MFMA attention -> split attb (overwrites h_hi/h_lo region)
        attn_flash_kernel<<<512, 256, 0, stream>>>(
            qkv_hi, qkv_lo, (l == 0) ? bias : (const u16*)nullptr, attb_hi, attb_lo);
        // Wo projection + residual + fused bn1 stats: h2 = h + attb @ Wo
        gemm2_kernel<<<dim3(4, 64), 256, 0, stream>>>(
            attb_hi, attb_lo, 256, WL + 393216, WL + 458752, 256,
            h2, nullptr, nullptr, nullptr, 0, h, st1);
        bn_apply_kernel<<<1024, 256, 0, stream>>>(
            h2, h, h_hi, h_lo, st1, bn1g + l * 256, bn1b + l * 256);
        // FF1: relu(h @ W1 + b1) -> split ff (overwrites qkv region)
        gemm2_kernel<<<dim3(8, 64), 256, 0, stream>>>(
            h_hi, h_lo, 256, WL + 524288, WL + 655360, 512,
            nullptr, ff_hi, ff_lo, ffb1 + l * 512, 1, nullptr, nullptr);
        // FF2 + bias + residual + fused bn2 stats: h2 = h + ff @ W2 + b2
        gemm2_kernel<<<dim3(4, 64), 256, 0, stream>>>(
            ff_hi, ff_lo, 512, WL + 786432, WL + 917504, 256,
            h2, nullptr, nullptr, ffb2 + l * 256, 0, h, st2);
        if (l == 2)
            bn_apply_kernel<<<1024, 256, 0, stream>>>(
                h2, outh, nullptr, nullptr, st2, bn2g + l * 256, bn2b + l * 256);
        else
            bn_apply_kernel<<<1024, 256, 0, stream>>>(
                h2, h, h_hi, h_lo, st2, bn2g + l * 256, bn2b + l * 256);
    }
    graph_embed_kernel<<<BB, 256, 0, stream>>>(outh, outg);
}